// Round 1
// baseline (312.020 us; speedup 1.0000x reference)
//
#include <hip/hip_runtime.h>
#include <stdint.h>

#define BATCH 64
#define SLEN 512
#define HID 128
#define NHEAD 4
#define DPROJ 512            // HID * NHEAD
#define MTOT (BATCH * SLEN)  // 32768
#define SCALE 0.08838834764831845f
#define LOG2E 1.4426950408889634f

using short8 = __attribute__((ext_vector_type(8))) short;
using f32x4  = __attribute__((ext_vector_type(4))) float;
using u32x4  = __attribute__((ext_vector_type(4))) unsigned int;
using u32x2  = __attribute__((ext_vector_type(2))) unsigned int;
using us4    = __attribute__((ext_vector_type(4))) unsigned short;

__device__ __forceinline__ unsigned short f2bf(float f) {
  unsigned int u = __float_as_uint(f);
  u += 0x7fffu + ((u >> 16) & 1u);   // round-to-nearest-even
  return (unsigned short)(u >> 16);
}

// ---------------------------------------------------------------------------
// Kernel 0: prep. blocks 0..1023: weight cast+transpose (Wq pre-scaled by
// SCALE*log2(e) so attn uses exp2). blocks 1024..3071: enc fp32->bf16.
// blocks 3072..19455: mask -> bitmask.
// ---------------------------------------------------------------------------
__global__ __launch_bounds__(256) void prep_kernel(
    const float* __restrict__ Wq,
    const float* __restrict__ Wk,
    const float* __restrict__ Wv,
    const float* __restrict__ Wo,
    const float* __restrict__ enc,
    const int* __restrict__ mask,
    unsigned short* __restrict__ WT,
    unsigned short* __restrict__ WoT,
    unsigned short* __restrict__ encb,
    unsigned int* __restrict__ mbits)
{
  if (blockIdx.x < 1024) {
    int idx = blockIdx.x * 256 + threadIdx.x;
    int z = idx >> 16;
    int i = idx & 65535;
    if (z < 3) {
      const float* W = (z == 0) ? Wq : (z == 1) ? Wk : Wv;
      float scale = (z == 0) ? (SCALE * LOG2E) : 1.0f;  // exp2 form
      int k = i >> 9;
      int n = i & 511;
      WT[(size_t)z * 65536 + (size_t)n * 128 + k] = f2bf(W[i] * scale);
    } else {
      int k = i >> 7;
      int n = i & 127;
      WoT[(size_t)n * 512 + k] = f2bf(Wo[i]);
    }
  } else if (blockIdx.x < 3072) {
    size_t tid = (size_t)(blockIdx.x - 1024) * 256 + threadIdx.x;  // 0..524287
    const float* s = enc + tid * 8;
    f32x4 a0 = *(const f32x4*)(s);
    f32x4 a1 = *(const f32x4*)(s + 4);
    short8 v;
    #pragma unroll
    for (int j = 0; j < 4; ++j) v[j] = (short)f2bf(a0[j]);
    #pragma unroll
    for (int j = 0; j < 4; ++j) v[4 + j] = (short)f2bf(a1[j]);
    *(short8*)(encb + tid * 8) = v;
  } else {
    const int l = threadIdx.x & 63;
    size_t wavebase = (size_t)(blockIdx.x - 3072) * 1024 + (threadIdx.x >> 6) * 256;
    unsigned long long b0 = __ballot(mask[wavebase + 0 * 64 + l] != 0);
    unsigned long long b1 = __ballot(mask[wavebase + 1 * 64 + l] != 0);
    unsigned long long b2 = __ballot(mask[wavebase + 2 * 64 + l] != 0);
    unsigned long long b3 = __ballot(mask[wavebase + 3 * 64 + l] != 0);
    if (l < 4) {
      unsigned long long v = (l & 2) ? ((l & 1) ? b3 : b2) : ((l & 1) ? b1 : b0);
      *(unsigned long long*)(mbits + (wavebase >> 5) + l * 2) = v;
    }
  }
}

// ---------------------------------------------------------------------------
// Kernel 1: QKV projection. Grid (4 heads, 256 mt); z-loop inside; A staged
// once full-K (128x136), reused 3x. B restaged per 64-k half (128x72) ->
// LDS 53,248 B -> 3 blocks/CU.
// Q/K: swapped-operand MFMA (reg axis = d) -> packed us4 stores.
// V: written transposed (reg axis = s).
// ---------------------------------------------------------------------------
__global__ __launch_bounds__(256) void qkv_kernel(
    const unsigned short* __restrict__ encb,  // (M,128) bf16
    const unsigned short* __restrict__ WT,    // (3,512,128) bf16 n-major
    unsigned short* __restrict__ Qh,
    unsigned short* __restrict__ Kh,
    unsigned short* __restrict__ Vt)
{
  const int nt = blockIdx.x;   // 0..3 == head
  const int mt = blockIdx.y;   // 0..255
  const int t = threadIdx.x;
  const int lane = t & 63;
  const int w = t >> 6;
  const int quad = lane >> 4;
  const int l16 = lane & 15;

  __shared__ __align__(16) unsigned short Ald[128 * 136];  // 34816 B
  __shared__ __align__(16) unsigned short Bld[128 * 72];   // 18432 B

  const int m0 = mt * 128, n0 = nt * 128;
  const int wm = (w >> 1) * 64, wn = (w & 1) * 64;

  // stage A once: 128x128 shorts = 2048 vec8, 8 per thread
  #pragma unroll
  for (int i = 0; i < 8; ++i) {
    int idx = i * 256 + t;
    int row = idx >> 4;
    int col = (idx & 15) << 3;
    *(u32x4*)(Ald + row * 136 + col) =
        *(const u32x4*)(encb + (size_t)(m0 + row) * HID + col);
  }

  for (int z = 0; z < 3; ++z) {
    const unsigned short* Wz = WT + (size_t)z * DPROJ * HID;

    f32x4 acc[4][4];
    #pragma unroll
    for (int mi = 0; mi < 4; ++mi)
      #pragma unroll
      for (int ni = 0; ni < 4; ++ni)
        acc[mi][ni] = f32x4{0.f, 0.f, 0.f, 0.f};

    #pragma unroll
    for (int kc = 0; kc < 2; ++kc) {
      __syncthreads();   // also covers A visibility (z==0,kc==0) and Bld reuse
      // stage B half: 128 rows x 64 k = 1024 vec8, 4 per thread
      #pragma unroll
      for (int i = 0; i < 4; ++i) {
        int idx = i * 256 + t;
        int row = idx >> 3;
        int col = (idx & 7) << 3;
        *(u32x4*)(Bld + row * 72 + col) =
            *(const u32x4*)(Wz + (size_t)(n0 + row) * HID + kc * 64 + col);
      }
      __syncthreads();

      #pragma unroll
      for (int kk = 0; kk < 2; ++kk) {
        short8 a[4], bb[4];
        #pragma unroll
        for (int mi = 0; mi < 4; ++mi)
          a[mi] = *(const short8*)(Ald + (wm + mi * 16 + l16) * 136 + kc * 64 + kk * 32 + quad * 8);
        #pragma unroll
        for (int ni = 0; ni < 4; ++ni)
          bb[ni] = *(const short8*)(Bld + (wn + ni * 16 + l16) * 72 + kk * 32 + quad * 8);
        if (z < 2) {
          #pragma unroll
          for (int mi = 0; mi < 4; ++mi)
            #pragma unroll
            for (int ni = 0; ni < 4; ++ni)
              acc[mi][ni] = __builtin_amdgcn_mfma_f32_16x16x32_bf16(bb[ni], a[mi], acc[mi][ni], 0, 0, 0);
        } else {
          #pragma unroll
          for (int mi = 0; mi < 4; ++mi)
            #pragma unroll
            for (int ni = 0; ni < 4; ++ni)
              acc[mi][ni] = __builtin_amdgcn_mfma_f32_16x16x32_bf16(a[mi], bb[ni], acc[mi][ni], 0, 0, 0);
        }
      }
    }

    if (z < 2) {
      // D[n][m]: col(l16)=m-within-16, row(quad*4+r)=d-within-16
      unsigned short* outz = ((z == 0) ? Qh : Kh) + (size_t)nt * MTOT * HID;
      #pragma unroll
      for (int mi = 0; mi < 4; ++mi)
        #pragma unroll
        for (int ni = 0; ni < 4; ++ni) {
          int m = m0 + wm + mi * 16 + l16;
          int dbase = wn + ni * 16 + quad * 4;
          us4 pk;
          #pragma unroll
          for (int r = 0; r < 4; ++r) pk[r] = f2bf(acc[mi][ni][r]);
          *(us4*)(outz + (size_t)m * HID + dbase) = pk;
        }
    } else {
      // D[m][n]: reg axis = s (4 consecutive) -> Vt[(nt*B+b)*128 + d][s]
      #pragma unroll
      for (int mi = 0; mi < 4; ++mi)
        #pragma unroll
        for (int ni = 0; ni < 4; ++ni) {
          int row0 = m0 + wm + mi * 16 + quad * 4;
          int b = row0 >> 9, s = row0 & 511;
          int d = wn + ni * 16 + l16;
          us4 pk;
          #pragma unroll
          for (int r = 0; r < 4; ++r) pk[r] = f2bf(acc[mi][ni][r]);
          *(us4*)(Vt + ((size_t)(nt * BATCH + b) * HID + d) * SLEN + s) = pk;
        }
    }
  }
}

// ---------------------------------------------------------------------------
// Kernel 2: flash attention — R11 restructure. The R6/R10 version was
// LDS-throughput-bound (34 b128 reads + 16 b16 writes per wave-chunk ~=
// 143K LDS-pipe cycles/CU vs 152K total; MfmaUtil 22, VALU 30, HBM 17%).
// Changes:
//  * 256 threads / 4 waves, 32 q-rows per wave (mi=0,1): every K-frag and
//    V-frag ds_read_b128 now feeds TWO mfmas -> K/V LDS reads per q-row
//    halved. LDS tiles unchanged (54,272 B -> 3 blocks/CU, 12 waves/CU).
//  * Pld column XOR-swizzle col ^= ((row>>2)&3)<<3 (bits 3-4 only, so b128
//    reads stay contiguous): the 4 quads' b16 P-writes land on 4 disjoint
//    8-bank groups (was quad0/2 + quad1/3 colliding -> 8.9M conflict cyc).
//    Same XOR applied on the PV read side (key=(l16>>2)&3 == (row>>2)&3).
//  * K prefetch issued before QK^T, V prefetch after (kreg/vreg never
//    simultaneously live with sc) to stay under the 170-VGPR cap of
//    __launch_bounds__(256,3).
// ---------------------------------------------------------------------------
__global__ __launch_bounds__(256, 3) void attn_kernel(
    const unsigned short* __restrict__ Qh,   // (NH, M, 128)
    const unsigned short* __restrict__ Kh,   // (NH, M, 128)
    const unsigned short* __restrict__ Vt,   // (NH, B, 128, S)
    const unsigned int* __restrict__ mbits,  // (B, S, 16)
    unsigned short* __restrict__ ctx)        // (M, 512)
{
  const int lin = blockIdx.x;              // 0..1023
  const int work = (lin & 7) * 128 + (lin >> 3);
  const int qt = work & 3;
  const int h  = (work >> 2) & 3;
  const int b  = work >> 4;

  const int t = threadIdx.x;               // 0..255
  const int lane = t & 63;
  const int w = t >> 6;                    // 0..3
  const int quad = lane >> 4;
  const int l16 = lane & 15;

  __shared__ __align__(16) unsigned short Kld[64 * 136];   // 17408 B
  __shared__ __align__(16) unsigned short Vtld[128 * 72];  // 18432 B
  __shared__ __align__(16) unsigned short Pld[128 * 72];   // 18432 B

  const int q0 = qt * 128;
  const size_t rowbase = (size_t)b * SLEN;
  const unsigned short* kbase0 = Kh + ((size_t)h * MTOT + rowbase) * HID;
  const unsigned short* vbase  = Vt + (size_t)(h * BATCH + b) * HID * SLEN;
  const unsigned int* mrow = mbits + (size_t)b * SLEN * 16;

  const int k_key = t >> 4, k_col = (t & 15) << 3;   // +16 keys per i
  const int v_d   = t >> 3, v_cc  = (t & 7) << 3;    // +32 d per i

  // Q for this wave's 32 rows, held in registers across all chunks
  short8 qa[2][4];
  #pragma unroll
  for (int mi = 0; mi < 2; ++mi) {
    const unsigned short* qbase =
        Qh + ((size_t)h * MTOT + rowbase + q0 + w * 32 + mi * 16 + l16) * HID + quad * 8;
    #pragma unroll
    for (int kk = 0; kk < 4; ++kk)
      qa[mi][kk] = *(const short8*)(qbase + kk * 32);
  }

  short8 ones;
  #pragma unroll
  for (int j = 0; j < 8; ++j) ones[j] = (short)0x3F80;  // bf16 1.0

  f32x4 oc[2][8], oc9[2];
  #pragma unroll
  for (int mi = 0; mi < 2; ++mi) {
    #pragma unroll
    for (int nd = 0; nd < 8; ++nd) oc[mi][nd] = f32x4{0.f, 0.f, 0.f, 0.f};
    oc9[mi] = f32x4{0.f, 0.f, 0.f, 0.f};
  }

  // prefetch chunk 0 into registers (4 x 16B each for K and V)
  u32x4 kreg[4], vreg[4];
  #pragma unroll
  for (int i = 0; i < 4; ++i) {
    kreg[i] = *(const u32x4*)(kbase0 + (size_t)(k_key + i * 16) * HID + k_col);
    vreg[i] = *(const u32x4*)(vbase + (size_t)(v_d + i * 32) * SLEN + v_cc);
  }

  for (int c0 = 0; c0 < SLEN; c0 += 64) {
    if (c0) __syncthreads();   // prev chunk's LDS reads complete
    #pragma unroll
    for (int i = 0; i < 4; ++i) {
      *(u32x4*)(Kld + (k_key + i * 16) * 136 + k_col) = kreg[i];
      *(u32x4*)(Vtld + (v_d + i * 32) * 72 + v_cc) = vreg[i];
    }
    __syncthreads();

    // K prefetch for next chunk: latency covered by QK^T
    if (c0 + 64 < SLEN) {
      #pragma unroll
      for (int i = 0; i < 4; ++i)
        kreg[i] = *(const u32x4*)(kbase0 + (size_t)(c0 + 64 + k_key + i * 16) * HID + k_col);
    }

    // S = Q K^T (scale+log2e folded into Q); each bb read feeds both mi
    f32x4 sc[2][4];
    #pragma unroll
    for (int mi = 0; mi < 2; ++mi)
      #pragma unroll
      for (int ni = 0; ni < 4; ++ni) sc[mi][ni] = f32x4{0.f, 0.f, 0.f, 0.f};
    #pragma unroll
    for (int kk = 0; kk < 4; ++kk) {
      #pragma unroll
      for (int ni = 0; ni < 4; ++ni) {
        short8 bb = *(const short8*)(Kld + (ni * 16 + l16) * 136 + kk * 32 + quad * 8);
        sc[0][ni] = __builtin_amdgcn_mfma_f32_16x16x32_bf16(qa[0][kk], bb, sc[0][ni], 0, 0, 0);
        sc[1][ni] = __builtin_amdgcn_mfma_f32_16x16x32_bf16(qa[1][kk], bb, sc[1][ni], 0, 0, 0);
      }
    }

    // V prefetch for next chunk: latency covered by softmax + PV
    if (c0 + 64 < SLEN) {
      #pragma unroll
      for (int i = 0; i < 4; ++i)
        vreg[i] = *(const u32x4*)(vbase + (size_t)(v_d + i * 32) * SLEN + c0 + 64 + v_cc);
    }

    // p = mask ? exp2(s) : 0 ; write to Pld (wave-private rows -> fence only)
    // column swizzled by ((row>>2)&3)<<3 == quad<<3 -> 4 quads hit 4
    // disjoint 8-bank groups (conflict-free b16 writes)
    #pragma unroll
    for (int mi = 0; mi < 2; ++mi) {
      u32x2 mw[4];
      #pragma unroll
      for (int r = 0; r < 4; ++r) {
        int qrow = q0 + w * 32 + mi * 16 + quad * 4 + r;
        mw[r] = *(const u32x2*)(mrow + (size_t)qrow * 16 + (c0 >> 5));
      }
      #pragma unroll
      for (int ni = 0; ni < 4; ++ni) {
        int bit = (ni & 1) * 16 + l16;
        int colsw = (ni * 16 + l16) ^ (quad << 3);
        #pragma unroll
        for (int r = 0; r < 4; ++r) {
          unsigned wsel = (ni < 2) ? mw[r][0] : mw[r][1];
          float e = __builtin_amdgcn_exp2f(sc[mi][ni][r]);   // raw v_exp_f32
          float p = ((wsel >> bit) & 1u) ? e : 0.f;
          Pld[(w * 32 + mi * 16 + quad * 4 + r) * 72 + colsw] = f2bf(p);
        }
      }
    }
    __threadfence_block();

    // O += P @ V ; rowsum += P @ 1 ; each bv read feeds both mi
    const int rsw = (l16 >> 2) << 3;   // read-side swizzle key: (row>>2)&3
    #pragma unroll
    for (int kb = 0; kb < 2; ++kb) {
      short8 a0 = *(const short8*)(Pld + (w * 32 + l16) * 72 + ((kb * 32 + quad * 8) ^ rsw));
      short8 a1 = *(const short8*)(Pld + (w * 32 + 16 + l16) * 72 + ((kb * 32 + quad * 8) ^ rsw));
      #pragma unroll
      for (int nd = 0; nd < 8; ++nd) {
        short8 bv = *(const short8*)(Vtld + (nd * 16 + l16) * 72 + kb * 32 + quad * 8);
        oc[0][nd] = __builtin_amdgcn_mfma_f32_16x16x32_bf16(a0, bv, oc[0][nd], 0, 0, 0);
        oc[1][nd] = __builtin_amdgcn_mfma_f32_16x16x32_bf16(a1, bv, oc[1][nd], 0, 0, 0);
      }
      oc9[0] = __builtin_amdgcn_mfma_f32_16x16x32_bf16(a0, ones, oc9[0], 0, 0, 0);
      oc9[1] = __builtin_amdgcn_mfma_f32_16x16x32_bf16(a1, ones, oc9[1], 0, 0, 0);
    }
  }

  // D[q][d] epilogue: rcp once per row, multiply
  #pragma unroll
  for (int mi = 0; mi < 2; ++mi) {
    float rcp[4];
    #pragma unroll
    for (int r = 0; r < 4; ++r) rcp[r] = __builtin_amdgcn_rcpf(oc9[mi][r]);
    #pragma unroll
    for (int nd = 0; nd < 8; ++nd)
      #pragma unroll
      for (int r = 0; r < 4; ++r) {
        float val = oc[mi][nd][r] * rcp[r];
        int row = q0 + w * 32 + mi * 16 + quad * 4 + r;
        int col = h * HID + nd * 16 + l16;
        ctx[(rowbase + row) * DPROJ + col] = f2bf(val);
      }
  }
}

// ---------------------------------------------------------------------------
// Kernel 3: fused output projection + residual + LayerNorm (R8 version).
// ---------------------------------------------------------------------------
__global__ __launch_bounds__(256, 4) void oproj_ln_kernel(
    const unsigned short* __restrict__ ctx,   // (M,512) bf16
    const unsigned short* __restrict__ WoT,   // (128,512) bf16 n-major
    const float* __restrict__ enc,            // (M,128) fp32
    const float* __restrict__ gamma,
    const float* __restrict__ beta,
    float* __restrict__ out)                  // (M,128) fp32
{
  const int m0 = blockIdx.x * 64;
  const int t = threadIdx.x;
  const int lane = t & 63;
  const int w = t >> 6;
  const int quad = lane >> 4;
  const int l16 = lane & 15;

  __shared__ __align__(16) unsigned short Actx[64 * 72];
  __shared__ __align__(16) unsigned short Bw[128 * 72];

  f32x4 acc[8];
  #pragma unroll
  for (int ni = 0; ni < 8; ++ni) acc[ni] = f32x4{0.f, 0.f, 0.f, 0.f};

  for (int kc = 0; kc < DPROJ; kc += 64) {
    __syncthreads();
    #pragma unroll
    for (int i = 0; i < 2; ++i) {
      int idx = i * 256 + t;
      int row = idx >> 3;
      int col = (idx & 7) << 3;
      *(u32x4*)(Actx + row * 72 + col) =
          *(const u32x4*)(ctx + (size_t)(m0 + row) * DPROJ + kc + col);
    }
    #pragma unroll
    for (int i = 0; i < 4; ++i) {
      int idx = i * 256 + t;
      int row = idx >> 3;
      int col = (idx & 7) << 3;
      *(u32x4*)(Bw + row * 72 + col) =
          *(const u32x4*)(WoT + (size_t)row * DPROJ + kc + col);
    }
    __syncthreads();
    #pragma unroll
    for (int kk = 0; kk < 2; ++kk) {
      short8 a = *(const short8*)(Actx + (w * 16 + l16) * 72 + kk * 32 + quad * 8);
      #pragma unroll
      for (int ni = 0; ni < 8; ++ni) {
        short8 bb = *(const short8*)(Bw + (ni * 16 + l16) * 72 + kk * 32 + quad * 8);
        acc[ni] = __builtin_amdgcn_mfma_f32_16x16x32_bf16(a, bb, acc[ni], 0, 0, 0);
      }
    }
  }

  float g[8], be[8];
  #pragma unroll
  for (int ni = 0; ni < 8; ++ni) {
    g[ni] = gamma[ni * 16 + l16];
    be[ni] = beta[ni * 16 + l16];
  }

  float val[8][4];
  #pragma unroll
  for (int r = 0; r < 4; ++r) {
    int m = m0 + w * 16 + quad * 4 + r;
    const float* erow = enc + (size_t)m * HID;
    float s = 0.f, s2 = 0.f;
    #pragma unroll
    for (int ni = 0; ni < 8; ++ni) {
      float v = acc[ni][r] + erow[ni * 16 + l16];
      val[ni][r] = v;
      s += v;
      s2 += v * v;
    }
    #pragma unroll
    for (int off = 1; off < 16; off <<= 1) {
      s  += __shfl_xor(s, off, 64);
      s2 += __shfl_xor(s2, off, 64);
    }
    float mean = s * (1.f / 128.f);
    float var = s2 * (1.f / 128.f) - mean * mean;
    float rstd = rsqrtf(var + 1e-6f);
    float* orow = out + (size_t)m * HID;
    #pragma unroll
    for (int ni = 0; ni < 8; ++ni)
      orow[ni * 16 + l16] = g[ni] * (val[ni][r] - mean) * rstd + be[ni];
  }
}

// ---------------------------------------------------------------------------
// ws layout (elements):
//   WT   : 3*512*128 shorts        WoT : 128*512 shorts
//   Qh   : 4*M*128 shorts          Kh  : 4*M*128 shorts
//   Vt   : 4*64*128*512 shorts     ctx : M*512 shorts
//   encb : M*128 shorts (fp32-sized slot)
//   mbits: 64*512*16 u32           (~153.6 MB total)
// ---------------------------------------------------------------------------
extern "C" void kernel_launch(void* const* d_in, const int* in_sizes, int n_in,
                              void* d_out, int out_size, void* d_ws, size_t ws_size,
                              hipStream_t stream) {
  const float* enc   = (const float*)d_in[0];
  const int*   mask  = (const int*)d_in[1];
  const float* Wq    = (const float*)d_in[2];
  const float* Wk    = (const float*)d_in[3];
  const float* Wv    = (const float*)d_in[4];
  const float* Wo    = (const float*)d_in[5];
  const float* gamma = (const float*)d_in[6];
  const float* beta  = (const float*)d_in[7];
  float* out = (float*)d_out;

  unsigned short* WT  = (unsigned short*)d_ws;
  unsigned short* WoT = WT + (size_t)3 * DPROJ * HID;
  unsigned short* Qh  = WoT + (size_t)HID * DPROJ;
  unsigned short* Kh  = Qh + (size_t)NHEAD * MTOT * HID;
  unsigned short* Vt  = Kh + (size_t)NHEAD * MTOT * HID;
  unsigned short* ctx = Vt + (size_t)NHEAD * MTOT * HID;
  unsigned short* encb = ctx + (size_t)MTOT * DPROJ;
  unsigned int* mbits = (unsigned int*)(encb + (size_t)MTOT * HID * 2);

  prep_kernel<<<19456, 256, 0, stream>>>(Wq, Wk, Wv, Wo, enc, mask, WT, WoT, encb, mbits);
  qkv_kernel<<<dim3(4, 256), 256, 0, stream>>>(encb, WT, Qh, Kh, Vt);
  attn_kernel<<<1024, 256, 0, stream>>>(Qh, Kh, Vt, mbits, ctx);
  oproj_ln_kernel<<<MTOT / 64, 256, 0, stream>>>(ctx, WoT, enc, gamma, beta, out);
}

// Round 2
// 228.719 us; speedup vs baseline: 1.3642x; 1.3642x over previous
//
#include <hip/hip_runtime.h>
#include <stdint.h>

#define BATCH 64
#define SLEN 512
#define HID 128
#define NHEAD 4
#define DPROJ 512            // HID * NHEAD
#define MTOT (BATCH * SLEN)  // 32768
#define SCALE 0.08838834764831845f
#define LOG2E 1.4426950408889634f

using short8 = __attribute__((ext_vector_type(8))) short;
using f32x4  = __attribute__((ext_vector_type(4))) float;
using u32x4  = __attribute__((ext_vector_type(4))) unsigned int;
using u32x2  = __attribute__((ext_vector_type(2))) unsigned int;
using us4    = __attribute__((ext_vector_type(4))) unsigned short;

__device__ __forceinline__ unsigned short f2bf(float f) {
  unsigned int u = __float_as_uint(f);
  u += 0x7fffu + ((u >> 16) & 1u);   // round-to-nearest-even
  return (unsigned short)(u >> 16);
}

// ---------------------------------------------------------------------------
// Kernel 0: prep. blocks 0..1023: weight cast+transpose (Wq pre-scaled by
// SCALE*log2(e) so attn uses exp2). blocks 1024..3071: enc fp32->bf16.
// blocks 3072..19455: mask -> bitmask.
// ---------------------------------------------------------------------------
__global__ __launch_bounds__(256) void prep_kernel(
    const float* __restrict__ Wq,
    const float* __restrict__ Wk,
    const float* __restrict__ Wv,
    const float* __restrict__ Wo,
    const float* __restrict__ enc,
    const int* __restrict__ mask,
    unsigned short* __restrict__ WT,
    unsigned short* __restrict__ WoT,
    unsigned short* __restrict__ encb,
    unsigned int* __restrict__ mbits)
{
  if (blockIdx.x < 1024) {
    int idx = blockIdx.x * 256 + threadIdx.x;
    int z = idx >> 16;
    int i = idx & 65535;
    if (z < 3) {
      const float* W = (z == 0) ? Wq : (z == 1) ? Wk : Wv;
      float scale = (z == 0) ? (SCALE * LOG2E) : 1.0f;  // exp2 form
      int k = i >> 9;
      int n = i & 511;
      WT[(size_t)z * 65536 + (size_t)n * 128 + k] = f2bf(W[i] * scale);
    } else {
      int k = i >> 7;
      int n = i & 127;
      WoT[(size_t)n * 512 + k] = f2bf(Wo[i]);
    }
  } else if (blockIdx.x < 3072) {
    size_t tid = (size_t)(blockIdx.x - 1024) * 256 + threadIdx.x;  // 0..524287
    const float* s = enc + tid * 8;
    f32x4 a0 = *(const f32x4*)(s);
    f32x4 a1 = *(const f32x4*)(s + 4);
    short8 v;
    #pragma unroll
    for (int j = 0; j < 4; ++j) v[j] = (short)f2bf(a0[j]);
    #pragma unroll
    for (int j = 0; j < 4; ++j) v[4 + j] = (short)f2bf(a1[j]);
    *(short8*)(encb + tid * 8) = v;
  } else {
    const int l = threadIdx.x & 63;
    size_t wavebase = (size_t)(blockIdx.x - 3072) * 1024 + (threadIdx.x >> 6) * 256;
    unsigned long long b0 = __ballot(mask[wavebase + 0 * 64 + l] != 0);
    unsigned long long b1 = __ballot(mask[wavebase + 1 * 64 + l] != 0);
    unsigned long long b2 = __ballot(mask[wavebase + 2 * 64 + l] != 0);
    unsigned long long b3 = __ballot(mask[wavebase + 3 * 64 + l] != 0);
    if (l < 4) {
      unsigned long long v = (l & 2) ? ((l & 1) ? b3 : b2) : ((l & 1) ? b1 : b0);
      *(unsigned long long*)(mbits + (wavebase >> 5) + l * 2) = v;
    }
  }
}

// ---------------------------------------------------------------------------
// Kernel 1: QKV projection (unchanged from the 233us version).
// ---------------------------------------------------------------------------
__global__ __launch_bounds__(256) void qkv_kernel(
    const unsigned short* __restrict__ encb,  // (M,128) bf16
    const unsigned short* __restrict__ WT,    // (3,512,128) bf16 n-major
    unsigned short* __restrict__ Qh,
    unsigned short* __restrict__ Kh,
    unsigned short* __restrict__ Vt)
{
  const int nt = blockIdx.x;   // 0..3 == head
  const int mt = blockIdx.y;   // 0..255
  const int t = threadIdx.x;
  const int lane = t & 63;
  const int w = t >> 6;
  const int quad = lane >> 4;
  const int l16 = lane & 15;

  __shared__ __align__(16) unsigned short Ald[128 * 136];  // 34816 B
  __shared__ __align__(16) unsigned short Bld[128 * 72];   // 18432 B

  const int m0 = mt * 128, n0 = nt * 128;
  const int wm = (w >> 1) * 64, wn = (w & 1) * 64;

  // stage A once: 128x128 shorts = 2048 vec8, 8 per thread
  #pragma unroll
  for (int i = 0; i < 8; ++i) {
    int idx = i * 256 + t;
    int row = idx >> 4;
    int col = (idx & 15) << 3;
    *(u32x4*)(Ald + row * 136 + col) =
        *(const u32x4*)(encb + (size_t)(m0 + row) * HID + col);
  }

  for (int z = 0; z < 3; ++z) {
    const unsigned short* Wz = WT + (size_t)z * DPROJ * HID;

    f32x4 acc[4][4];
    #pragma unroll
    for (int mi = 0; mi < 4; ++mi)
      #pragma unroll
      for (int ni = 0; ni < 4; ++ni)
        acc[mi][ni] = f32x4{0.f, 0.f, 0.f, 0.f};

    #pragma unroll
    for (int kc = 0; kc < 2; ++kc) {
      __syncthreads();   // also covers A visibility (z==0,kc==0) and Bld reuse
      // stage B half: 128 rows x 64 k = 1024 vec8, 4 per thread
      #pragma unroll
      for (int i = 0; i < 4; ++i) {
        int idx = i * 256 + t;
        int row = idx >> 3;
        int col = (idx & 7) << 3;
        *(u32x4*)(Bld + row * 72 + col) =
            *(const u32x4*)(Wz + (size_t)(n0 + row) * HID + kc * 64 + col);
      }
      __syncthreads();

      #pragma unroll
      for (int kk = 0; kk < 2; ++kk) {
        short8 a[4], bb[4];
        #pragma unroll
        for (int mi = 0; mi < 4; ++mi)
          a[mi] = *(const short8*)(Ald + (wm + mi * 16 + l16) * 136 + kc * 64 + kk * 32 + quad * 8);
        #pragma unroll
        for (int ni = 0; ni < 4; ++ni)
          bb[ni] = *(const short8*)(Bld + (wn + ni * 16 + l16) * 72 + kk * 32 + quad * 8);
        if (z < 2) {
          #pragma unroll
          for (int mi = 0; mi < 4; ++mi)
            #pragma unroll
            for (int ni = 0; ni < 4; ++ni)
              acc[mi][ni] = __builtin_amdgcn_mfma_f32_16x16x32_bf16(bb[ni], a[mi], acc[mi][ni], 0, 0, 0);
        } else {
          #pragma unroll
          for (int mi = 0; mi < 4; ++mi)
            #pragma unroll
            for (int ni = 0; ni < 4; ++ni)
              acc[mi][ni] = __builtin_amdgcn_mfma_f32_16x16x32_bf16(a[mi], bb[ni], acc[mi][ni], 0, 0, 0);
        }
      }
    }

    if (z < 2) {
      // D[n][m]: col(l16)=m-within-16, row(quad*4+r)=d-within-16
      unsigned short* outz = ((z == 0) ? Qh : Kh) + (size_t)nt * MTOT * HID;
      #pragma unroll
      for (int mi = 0; mi < 4; ++mi)
        #pragma unroll
        for (int ni = 0; ni < 4; ++ni) {
          int m = m0 + wm + mi * 16 + l16;
          int dbase = wn + ni * 16 + quad * 4;
          us4 pk;
          #pragma unroll
          for (int r = 0; r < 4; ++r) pk[r] = f2bf(acc[mi][ni][r]);
          *(us4*)(outz + (size_t)m * HID + dbase) = pk;
        }
    } else {
      // D[m][n]: reg axis = s (4 consecutive) -> Vt[(nt*B+b)*128 + d][s]
      #pragma unroll
      for (int mi = 0; mi < 4; ++mi)
        #pragma unroll
        for (int ni = 0; ni < 4; ++ni) {
          int row0 = m0 + wm + mi * 16 + quad * 4;
          int b = row0 >> 9, s = row0 & 511;
          int d = wn + ni * 16 + l16;
          us4 pk;
          #pragma unroll
          for (int r = 0; r < 4; ++r) pk[r] = f2bf(acc[mi][ni][r]);
          *(us4*)(Vt + ((size_t)(nt * BATCH + b) * HID + d) * SLEN + s) = pk;
        }
    }
  }
}

// ---------------------------------------------------------------------------
// Kernel 2: flash attention — R12. Base = R6/R10 512-thread structure
// (measured 63us, VGPR 60; the R11 2x-q-row restructure spilled: WRITE_SIZE
// 32->263MB scratch, reverted). Change: eliminate the Pld LDS round-trip.
//  * QK^T operands SWAPPED: mfma(K_frag, Q_frag) -> S^T; lane l16 = q-row,
//    regs (ni,quad,r) = 16 keys. A/B frag layouts are identical for
//    16x16x32, so same LDS reads / same qa registers.
//  * mask: one u32x2 per lane per chunk (was 4).
//  * P -> PV A-frag built IN REGISTERS: 8x v_cvt_pk_bf16_f32 then
//    4x v_permlane32_swap + 4x v_permlane16_swap (pure VALU):
//    frag[kb] dword c must hold keys kb*32+quad*8+2c+{0,1} =
//    pk[2kb+(quad>>1)][c&1] sourced from quad' 2(quad&1)+(c>>1);
//    pl32swap(a=pk[2kb][b], t=pk[2kb+1][b]) -> s0=(a.q0,a.q1,t.q0,t.q1),
//    s1=(a.q2,a.q3,t.q2,t.q3); pl16swap(s0,s1) -> (a.q0,a.q2,t.q0,t.q2)=c=b
//    and (a.q1,a.q3,t.q1,t.q3)=c=b+2. Verified elementwise.
//  * Deletes: 16 ds_write_b16 (the 4-way-conflict source, 8.9M cyc),
//    2 ds_read_b128, threadfence, 18KB LDS. LDS ops/wave-chunk 54->36;
//    LDS block 54,272 -> 35,840 B.
// ---------------------------------------------------------------------------
__global__ __launch_bounds__(512, 4) void attn_kernel(
    const unsigned short* __restrict__ Qh,   // (NH, M, 128)
    const unsigned short* __restrict__ Kh,   // (NH, M, 128)
    const unsigned short* __restrict__ Vt,   // (NH, B, 128, S)
    const unsigned int* __restrict__ mbits,  // (B, S, 16)
    unsigned short* __restrict__ ctx)        // (M, 512)
{
  const int lin = blockIdx.x;              // 0..1023
  const int work = (lin & 7) * 128 + (lin >> 3);
  const int qt = work & 3;
  const int h  = (work >> 2) & 3;
  const int b  = work >> 4;

  const int t = threadIdx.x;
  const int lane = t & 63;
  const int w = t >> 6;                    // 0..7
  const int quad = lane >> 4;
  const int l16 = lane & 15;

  __shared__ __align__(16) unsigned short Kld[64 * 136];   // 17408 B
  __shared__ __align__(16) unsigned short Vtld[128 * 72];  // 18432 B

  const int q0 = qt * 128;
  const size_t rowbase = (size_t)b * SLEN;
  const unsigned short* kbase0 = Kh + ((size_t)h * MTOT + rowbase) * HID;
  const unsigned short* vbase  = Vt + (size_t)(h * BATCH + b) * HID * SLEN;
  const unsigned int* mrow = mbits + (size_t)b * SLEN * 16;

  const int k_key = t >> 4, k_col = (t & 15) << 3;   // +32 keys at i=1
  const int v_d   = t >> 3, v_cc  = (t & 7) << 3;    // +64 d at i=1

  short8 qa[4];
  {
    const unsigned short* qbase =
        Qh + ((size_t)h * MTOT + rowbase + q0 + w * 16 + l16) * HID + quad * 8;
    #pragma unroll
    for (int kk = 0; kk < 4; ++kk)
      qa[kk] = *(const short8*)(qbase + kk * 32);
  }

  short8 ones;
  #pragma unroll
  for (int j = 0; j < 8; ++j) ones[j] = (short)0x3F80;  // bf16 1.0

  f32x4 oc[8], oc9;
  #pragma unroll
  for (int nd = 0; nd < 8; ++nd) oc[nd] = f32x4{0.f, 0.f, 0.f, 0.f};
  oc9 = f32x4{0.f, 0.f, 0.f, 0.f};

  // prefetch chunk 0 into registers
  u32x4 kreg[2], vreg[2];
  #pragma unroll
  for (int i = 0; i < 2; ++i) {
    kreg[i] = *(const u32x4*)(kbase0 + (size_t)(k_key + i * 32) * HID + k_col);
    vreg[i] = *(const u32x4*)(vbase + (size_t)(v_d + i * 64) * SLEN + v_cc);
  }

  // per-lane q-row is fixed: one mask base
  const unsigned int* mq = mrow + (size_t)(q0 + w * 16 + l16) * 16;

  for (int c0 = 0; c0 < SLEN; c0 += 64) {
    if (c0) __syncthreads();   // prev chunk's LDS reads complete
    #pragma unroll
    for (int i = 0; i < 2; ++i) {
      *(u32x4*)(Kld + (k_key + i * 32) * 136 + k_col) = kreg[i];
      *(u32x4*)(Vtld + (v_d + i * 64) * 72 + v_cc) = vreg[i];
    }
    __syncthreads();
    if (c0 + 64 < SLEN) {
      #pragma unroll
      for (int i = 0; i < 2; ++i) {
        kreg[i] = *(const u32x4*)(kbase0 + (size_t)(c0 + 64 + k_key + i * 32) * HID + k_col);
        vreg[i] = *(const u32x4*)(vbase + (size_t)(v_d + i * 64) * SLEN + c0 + 64 + v_cc);
      }
    }

    // mask bits: 64 keys for this lane's q-row
    u32x2 mw = *(const u32x2*)(mq + (c0 >> 5));

    // S^T = (Q K^T)^T via swapped operands: lane l16 = q, regs = keys
    f32x4 sc[4];
    #pragma unroll
    for (int ni = 0; ni < 4; ++ni) sc[ni] = f32x4{0.f, 0.f, 0.f, 0.f};
    #pragma unroll
    for (int kk = 0; kk < 4; ++kk) {
      #pragma unroll
      for (int ni = 0; ni < 4; ++ni) {
        short8 bb = *(const short8*)(Kld + (ni * 16 + l16) * 136 + kk * 32 + quad * 8);
        sc[ni] = __builtin_amdgcn_mfma_f32_16x16x32_bf16(bb, qa[kk], sc[ni], 0, 0, 0);
      }
    }

    // p = mask ? exp2(s) : 0, packed to bf16 pairs in-register
    unsigned int pk[4][2];
    #pragma unroll
    for (int ni = 0; ni < 4; ++ni) {
      unsigned wsel = (ni < 2) ? mw[0] : mw[1];
      float p[4];
      #pragma unroll
      for (int r = 0; r < 4; ++r) {
        int bit = (ni & 1) * 16 + quad * 4 + r;
        float e = __builtin_amdgcn_exp2f(sc[ni][r]);   // raw v_exp_f32
        p[r] = ((wsel >> bit) & 1u) ? e : 0.f;
      }
      asm("v_cvt_pk_bf16_f32 %0, %1, %2" : "=v"(pk[ni][0]) : "v"(p[0]), "v"(p[1]));
      asm("v_cvt_pk_bf16_f32 %0, %1, %2" : "=v"(pk[ni][1]) : "v"(p[2]), "v"(p[3]));
    }

    // O += P @ V ; rowsum += P @ 1 ; P A-frags assembled via permlane swaps
    #pragma unroll
    for (int kb = 0; kb < 2; ++kb) {
      unsigned int c0w = pk[kb * 2][0], c2w = pk[kb * 2 + 1][0];
      asm("v_permlane32_swap_b32 %0, %1" : "+v"(c0w), "+v"(c2w));
      asm("v_permlane16_swap_b32 %0, %1" : "+v"(c0w), "+v"(c2w));
      unsigned int c1w = pk[kb * 2][1], c3w = pk[kb * 2 + 1][1];
      asm("v_permlane32_swap_b32 %0, %1" : "+v"(c1w), "+v"(c3w));
      asm("v_permlane16_swap_b32 %0, %1" : "+v"(c1w), "+v"(c3w));
      short8 a = __builtin_bit_cast(short8, u32x4{c0w, c1w, c2w, c3w});
      #pragma unroll
      for (int nd = 0; nd < 8; ++nd) {
        short8 bv = *(const short8*)(Vtld + (nd * 16 + l16) * 72 + kb * 32 + quad * 8);
        oc[nd] = __builtin_amdgcn_mfma_f32_16x16x32_bf16(a, bv, oc[nd], 0, 0, 0);
      }
      oc9 = __builtin_amdgcn_mfma_f32_16x16x32_bf16(a, ones, oc9, 0, 0, 0);
    }
  }

  // D[q][d] epilogue: rcp once per row, multiply
  float rcp[4];
  #pragma unroll
  for (int r = 0; r < 4; ++r) rcp[r] = __builtin_amdgcn_rcpf(oc9[r]);
  #pragma unroll
  for (int nd = 0; nd < 8; ++nd)
    #pragma unroll
    for (int r = 0; r < 4; ++r) {
      float val = oc[nd][r] * rcp[r];
      int row = q0 + w * 16 + quad * 4 + r;
      int col = h * HID + nd * 16 + l16;
      ctx[(rowbase + row) * DPROJ + col] = f2bf(val);
    }
}

// ---------------------------------------------------------------------------
// Kernel 3: fused output projection + residual + LayerNorm (R8 version).
// ---------------------------------------------------------------------------
__global__ __launch_bounds__(256, 4) void oproj_ln_kernel(
    const unsigned short* __restrict__ ctx,   // (M,512) bf16
    const unsigned short* __restrict__ WoT,   // (128,512) bf16 n-major
    const float* __restrict__ enc,            // (M,128) fp32
    const float* __restrict__ gamma,
    const float* __restrict__ beta,
    float* __restrict__ out)                  // (M,128) fp32
{
  const int m0 = blockIdx.x * 64;
  const int t = threadIdx.x;
  const int lane = t & 63;
  const int w = t >> 6;
  const int quad = lane >> 4;
  const int l16 = lane & 15;

  __shared__ __align__(16) unsigned short Actx[64 * 72];
  __shared__ __align__(16) unsigned short Bw[128 * 72];

  f32x4 acc[8];
  #pragma unroll
  for (int ni = 0; ni < 8; ++ni) acc[ni] = f32x4{0.f, 0.f, 0.f, 0.f};

  for (int kc = 0; kc < DPROJ; kc += 64) {
    __syncthreads();
    #pragma unroll
    for (int i = 0; i < 2; ++i) {
      int idx = i * 256 + t;
      int row = idx >> 3;
      int col = (idx & 7) << 3;
      *(u32x4*)(Actx + row * 72 + col) =
          *(const u32x4*)(ctx + (size_t)(m0 + row) * DPROJ + kc + col);
    }
    #pragma unroll
    for (int i = 0; i < 4; ++i) {
      int idx = i * 256 + t;
      int row = idx >> 3;
      int col = (idx & 7) << 3;
      *(u32x4*)(Bw + row * 72 + col) =
          *(const u32x4*)(WoT + (size_t)row * DPROJ + kc + col);
    }
    __syncthreads();
    #pragma unroll
    for (int kk = 0; kk < 2; ++kk) {
      short8 a = *(const short8*)(Actx + (w * 16 + l16) * 72 + kk * 32 + quad * 8);
      #pragma unroll
      for (int ni = 0; ni < 8; ++ni) {
        short8 bb = *(const short8*)(Bw + (ni * 16 + l16) * 72 + kk * 32 + quad * 8);
        acc[ni] = __builtin_amdgcn_mfma_f32_16x16x32_bf16(a, bb, acc[ni], 0, 0, 0);
      }
    }
  }

  float g[8], be[8];
  #pragma unroll
  for (int ni = 0; ni < 8; ++ni) {
    g[ni] = gamma[ni * 16 + l16];
    be[ni] = beta[ni * 16 + l16];
  }

  float val[8][4];
  #pragma unroll
  for (int r = 0; r < 4; ++r) {
    int m = m0 + w * 16 + quad * 4 + r;
    const float* erow = enc + (size_t)m * HID;
    float s = 0.f, s2 = 0.f;
    #pragma unroll
    for (int ni = 0; ni < 8; ++ni) {
      float v = acc[ni][r] + erow[ni * 16 + l16];
      val[ni][r] = v;
      s += v;
      s2 += v * v;
    }
    #pragma unroll
    for (int off = 1; off < 16; off <<= 1) {
      s  += __shfl_xor(s, off, 64);
      s2 += __shfl_xor(s2, off, 64);
    }
    float mean = s * (1.f / 128.f);
    float var = s2 * (1.f / 128.f) - mean * mean;
    float rstd = rsqrtf(var + 1e-6f);
    float* orow = out + (size_t)m * HID;
    #pragma unroll
    for (int ni = 0; ni < 8; ++ni)
      orow[ni * 16 + l16] = g[ni] * (val[ni][r] - mean) * rstd + be[ni];
  }
}

// ---------------------------------------------------------------------------
// ws layout (elements):
//   WT   : 3*512*128 shorts        WoT : 128*512 shorts
//   Qh   : 4*M*128 shorts          Kh  : 4*M*128 shorts
//   Vt   : 4*64*128*512 shorts     ctx : M*512 shorts
//   encb : M*128 shorts (fp32-sized slot)
//   mbits: 64*512*16 u32           (~153.6 MB total)
// ---------------------------------------------------------------------------
extern "C" void kernel_launch(void* const* d_in, const int* in_sizes, int n_in,
                              void* d_out, int out_size, void* d_ws, size_t ws_size,
                              hipStream_t stream) {
  const float* enc   = (const float*)d_in[0];
  const int*   mask  = (const int*)d_in[1];
  const float* Wq    = (const float*)d_in[2];
  const float* Wk    = (const float*)d_in[3];
  const float* Wv    = (const float*)d_in[4];
  const float* Wo    = (const float*)d_in[5];
  const float* gamma = (const float*)d_in[6];
  const float* beta  = (const float*)d_in[7];
  float* out = (float*)d_out;

  unsigned short* WT  = (unsigned short*)d_ws;
  unsigned short* WoT = WT + (size_t)3 * DPROJ * HID;
  unsigned short* Qh  = WoT + (size_t)HID * DPROJ;
  unsigned short* Kh  = Qh + (size_t)NHEAD * MTOT * HID;
  unsigned short* Vt  = Kh + (size_t)NHEAD * MTOT * HID;
  unsigned short* ctx = Vt + (size_t)NHEAD * MTOT * HID;
  unsigned short* encb = ctx + (size_t)MTOT * DPROJ;
  unsigned int* mbits = (unsigned int*)(encb + (size_t)MTOT * HID * 2);

  prep_kernel<<<19456, 256, 0, stream>>>(Wq, Wk, Wv, Wo, enc, mask, WT, WoT, encb, mbits);
  qkv_kernel<<<dim3(4, 256), 256, 0, stream>>>(encb, WT, Qh, Kh, Vt);
  attn_kernel<<<1024, 512, 0, stream>>>(Qh, Kh, Vt, mbits, ctx);
  oproj_ln_kernel<<<MTOT / 64, 256, 0, stream>>>(ctx, WoT, enc, gamma, beta, out);
}

// Round 3
// 228.379 us; speedup vs baseline: 1.3662x; 1.0015x over previous
//
#include <hip/hip_runtime.h>
#include <stdint.h>

#define BATCH 64
#define SLEN 512
#define HID 128
#define NHEAD 4
#define DPROJ 512            // HID * NHEAD
#define MTOT (BATCH * SLEN)  // 32768
#define SCALE 0.08838834764831845f
#define LOG2E 1.4426950408889634f

using short8 = __attribute__((ext_vector_type(8))) short;
using f32x4  = __attribute__((ext_vector_type(4))) float;
using u32x4  = __attribute__((ext_vector_type(4))) unsigned int;
using u32x2  = __attribute__((ext_vector_type(2))) unsigned int;
using us4    = __attribute__((ext_vector_type(4))) unsigned short;

__device__ __forceinline__ unsigned short f2bf(float f) {
  unsigned int u = __float_as_uint(f);
  u += 0x7fffu + ((u >> 16) & 1u);   // round-to-nearest-even
  return (unsigned short)(u >> 16);
}

// ---------------------------------------------------------------------------
// Kernel 0: prep. blocks 0..1023: weight cast+transpose (Wq pre-scaled by
// SCALE*log2(e) so attn uses exp2). blocks 1024..3071: enc fp32->bf16.
// blocks 3072..19455: mask -> bitmask.
// ---------------------------------------------------------------------------
__global__ __launch_bounds__(256) void prep_kernel(
    const float* __restrict__ Wq,
    const float* __restrict__ Wk,
    const float* __restrict__ Wv,
    const float* __restrict__ Wo,
    const float* __restrict__ enc,
    const int* __restrict__ mask,
    unsigned short* __restrict__ WT,
    unsigned short* __restrict__ WoT,
    unsigned short* __restrict__ encb,
    unsigned int* __restrict__ mbits)
{
  if (blockIdx.x < 1024) {
    int idx = blockIdx.x * 256 + threadIdx.x;
    int z = idx >> 16;
    int i = idx & 65535;
    if (z < 3) {
      const float* W = (z == 0) ? Wq : (z == 1) ? Wk : Wv;
      float scale = (z == 0) ? (SCALE * LOG2E) : 1.0f;  // exp2 form
      int k = i >> 9;
      int n = i & 511;
      WT[(size_t)z * 65536 + (size_t)n * 128 + k] = f2bf(W[i] * scale);
    } else {
      int k = i >> 7;
      int n = i & 127;
      WoT[(size_t)n * 512 + k] = f2bf(Wo[i]);
    }
  } else if (blockIdx.x < 3072) {
    size_t tid = (size_t)(blockIdx.x - 1024) * 256 + threadIdx.x;  // 0..524287
    const float* s = enc + tid * 8;
    f32x4 a0 = *(const f32x4*)(s);
    f32x4 a1 = *(const f32x4*)(s + 4);
    short8 v;
    #pragma unroll
    for (int j = 0; j < 4; ++j) v[j] = (short)f2bf(a0[j]);
    #pragma unroll
    for (int j = 0; j < 4; ++j) v[4 + j] = (short)f2bf(a1[j]);
    *(short8*)(encb + tid * 8) = v;
  } else {
    const int l = threadIdx.x & 63;
    size_t wavebase = (size_t)(blockIdx.x - 3072) * 1024 + (threadIdx.x >> 6) * 256;
    unsigned long long b0 = __ballot(mask[wavebase + 0 * 64 + l] != 0);
    unsigned long long b1 = __ballot(mask[wavebase + 1 * 64 + l] != 0);
    unsigned long long b2 = __ballot(mask[wavebase + 2 * 64 + l] != 0);
    unsigned long long b3 = __ballot(mask[wavebase + 3 * 64 + l] != 0);
    if (l < 4) {
      unsigned long long v = (l & 2) ? ((l & 1) ? b3 : b2) : ((l & 1) ? b1 : b0);
      *(unsigned long long*)(mbits + (wavebase >> 5) + l * 2) = v;
    }
  }
}

// ---------------------------------------------------------------------------
// Kernel 1: QKV projection (unchanged from the 233us version).
// ---------------------------------------------------------------------------
__global__ __launch_bounds__(256) void qkv_kernel(
    const unsigned short* __restrict__ encb,  // (M,128) bf16
    const unsigned short* __restrict__ WT,    // (3,512,128) bf16 n-major
    unsigned short* __restrict__ Qh,
    unsigned short* __restrict__ Kh,
    unsigned short* __restrict__ Vt)
{
  const int nt = blockIdx.x;   // 0..3 == head
  const int mt = blockIdx.y;   // 0..255
  const int t = threadIdx.x;
  const int lane = t & 63;
  const int w = t >> 6;
  const int quad = lane >> 4;
  const int l16 = lane & 15;

  __shared__ __align__(16) unsigned short Ald[128 * 136];  // 34816 B
  __shared__ __align__(16) unsigned short Bld[128 * 72];   // 18432 B

  const int m0 = mt * 128, n0 = nt * 128;
  const int wm = (w >> 1) * 64, wn = (w & 1) * 64;

  // stage A once: 128x128 shorts = 2048 vec8, 8 per thread
  #pragma unroll
  for (int i = 0; i < 8; ++i) {
    int idx = i * 256 + t;
    int row = idx >> 4;
    int col = (idx & 15) << 3;
    *(u32x4*)(Ald + row * 136 + col) =
        *(const u32x4*)(encb + (size_t)(m0 + row) * HID + col);
  }

  for (int z = 0; z < 3; ++z) {
    const unsigned short* Wz = WT + (size_t)z * DPROJ * HID;

    f32x4 acc[4][4];
    #pragma unroll
    for (int mi = 0; mi < 4; ++mi)
      #pragma unroll
      for (int ni = 0; ni < 4; ++ni)
        acc[mi][ni] = f32x4{0.f, 0.f, 0.f, 0.f};

    #pragma unroll
    for (int kc = 0; kc < 2; ++kc) {
      __syncthreads();   // also covers A visibility (z==0,kc==0) and Bld reuse
      // stage B half: 128 rows x 64 k = 1024 vec8, 4 per thread
      #pragma unroll
      for (int i = 0; i < 4; ++i) {
        int idx = i * 256 + t;
        int row = idx >> 3;
        int col = (idx & 7) << 3;
        *(u32x4*)(Bld + row * 72 + col) =
            *(const u32x4*)(Wz + (size_t)(n0 + row) * HID + kc * 64 + col);
      }
      __syncthreads();

      #pragma unroll
      for (int kk = 0; kk < 2; ++kk) {
        short8 a[4], bb[4];
        #pragma unroll
        for (int mi = 0; mi < 4; ++mi)
          a[mi] = *(const short8*)(Ald + (wm + mi * 16 + l16) * 136 + kc * 64 + kk * 32 + quad * 8);
        #pragma unroll
        for (int ni = 0; ni < 4; ++ni)
          bb[ni] = *(const short8*)(Bld + (wn + ni * 16 + l16) * 72 + kk * 32 + quad * 8);
        if (z < 2) {
          #pragma unroll
          for (int mi = 0; mi < 4; ++mi)
            #pragma unroll
            for (int ni = 0; ni < 4; ++ni)
              acc[mi][ni] = __builtin_amdgcn_mfma_f32_16x16x32_bf16(bb[ni], a[mi], acc[mi][ni], 0, 0, 0);
        } else {
          #pragma unroll
          for (int mi = 0; mi < 4; ++mi)
            #pragma unroll
            for (int ni = 0; ni < 4; ++ni)
              acc[mi][ni] = __builtin_amdgcn_mfma_f32_16x16x32_bf16(a[mi], bb[ni], acc[mi][ni], 0, 0, 0);
        }
      }
    }

    if (z < 2) {
      // D[n][m]: col(l16)=m-within-16, row(quad*4+r)=d-within-16
      unsigned short* outz = ((z == 0) ? Qh : Kh) + (size_t)nt * MTOT * HID;
      #pragma unroll
      for (int mi = 0; mi < 4; ++mi)
        #pragma unroll
        for (int ni = 0; ni < 4; ++ni) {
          int m = m0 + wm + mi * 16 + l16;
          int dbase = wn + ni * 16 + quad * 4;
          us4 pk;
          #pragma unroll
          for (int r = 0; r < 4; ++r) pk[r] = f2bf(acc[mi][ni][r]);
          *(us4*)(outz + (size_t)m * HID + dbase) = pk;
        }
    } else {
      // D[m][n]: reg axis = s (4 consecutive) -> Vt[(nt*B+b)*128 + d][s]
      #pragma unroll
      for (int mi = 0; mi < 4; ++mi)
        #pragma unroll
        for (int ni = 0; ni < 4; ++ni) {
          int row0 = m0 + wm + mi * 16 + quad * 4;
          int b = row0 >> 9, s = row0 & 511;
          int d = wn + ni * 16 + l16;
          us4 pk;
          #pragma unroll
          for (int r = 0; r < 4; ++r) pk[r] = f2bf(acc[mi][ni][r]);
          *(us4*)(Vt + ((size_t)(nt * BATCH + b) * HID + d) * SLEN + s) = pk;
        }
    }
  }
}

// ---------------------------------------------------------------------------
// Kernel 2: flash attention — R13. Base = R12 (58.2us, VGPR 60, in-register
// softmax via swapped-QK^T + cvt_pk + permlane). R12 PMC: no pipe saturated
// (LDS ~53%, Mfma 26%, VALU 32%, HBM 18%) and BANK_CONFLICT is exactly
// 4/ds_read_b128 = structural -> latency/barrier-bound, not LDS-layout-bound.
// Changes (T3-lite 2-phase + T14 + T5):
//  * Double-buffered Kld/Vtld (71,680 B LDS, 2 blocks/CU). Loop body:
//    stage regs(c+1)->buf[p^1]; issue loads(c+2); compute(c) from buf[p];
//    lgkmcnt(0)+s_barrier. ONE barrier per chunk (was 2); stage-write
//    overlaps compute instead of serializing before it. Single-barrier
//    safety: readers of a buffer finish before the barrier that precedes
//    its next writer (both hazard directions checked).
//  * Raw s_waitcnt lgkmcnt(0) + s_barrier instead of __syncthreads():
//    avoids vmcnt(0) drain so the c+2 global loads stay in flight across
//    the barrier. ds_write/ds_read are memory ops, pinned by the "memory"
//    clobber (rule-18 hazard applies to register-only ops, not these).
//  * s_setprio(1) around the QK^T and PV MFMA clusters (T5, attn-positive).
// ---------------------------------------------------------------------------
__global__ __launch_bounds__(512, 4) void attn_kernel(
    const unsigned short* __restrict__ Qh,   // (NH, M, 128)
    const unsigned short* __restrict__ Kh,   // (NH, M, 128)
    const unsigned short* __restrict__ Vt,   // (NH, B, 128, S)
    const unsigned int* __restrict__ mbits,  // (B, S, 16)
    unsigned short* __restrict__ ctx)        // (M, 512)
{
  const int lin = blockIdx.x;              // 0..1023
  const int work = (lin & 7) * 128 + (lin >> 3);
  const int qt = work & 3;
  const int h  = (work >> 2) & 3;
  const int b  = work >> 4;

  const int t = threadIdx.x;
  const int lane = t & 63;
  const int w = t >> 6;                    // 0..7
  const int quad = lane >> 4;
  const int l16 = lane & 15;

  __shared__ __align__(16) unsigned short Kld[2][64 * 136];   // 34816 B
  __shared__ __align__(16) unsigned short Vtld[2][128 * 72];  // 36864 B

  const int q0 = qt * 128;
  const size_t rowbase = (size_t)b * SLEN;
  const unsigned short* kbase0 = Kh + ((size_t)h * MTOT + rowbase) * HID;
  const unsigned short* vbase  = Vt + (size_t)(h * BATCH + b) * HID * SLEN;
  const unsigned int* mrow = mbits + (size_t)b * SLEN * 16;

  const int k_key = t >> 4, k_col = (t & 15) << 3;   // +32 keys at i=1
  const int v_d   = t >> 3, v_cc  = (t & 7) << 3;    // +64 d at i=1

  short8 qa[4];
  {
    const unsigned short* qbase =
        Qh + ((size_t)h * MTOT + rowbase + q0 + w * 16 + l16) * HID + quad * 8;
    #pragma unroll
    for (int kk = 0; kk < 4; ++kk)
      qa[kk] = *(const short8*)(qbase + kk * 32);
  }

  short8 ones;
  #pragma unroll
  for (int j = 0; j < 8; ++j) ones[j] = (short)0x3F80;  // bf16 1.0

  f32x4 oc[8], oc9;
  #pragma unroll
  for (int nd = 0; nd < 8; ++nd) oc[nd] = f32x4{0.f, 0.f, 0.f, 0.f};
  oc9 = f32x4{0.f, 0.f, 0.f, 0.f};

  // per-lane q-row is fixed: one mask base
  const unsigned int* mq = mrow + (size_t)(q0 + w * 16 + l16) * 16;

  // prologue: load chunk 0 -> regs -> buf0; load chunk 1 -> regs; barrier
  u32x4 kreg[2], vreg[2];
  #pragma unroll
  for (int i = 0; i < 2; ++i) {
    kreg[i] = *(const u32x4*)(kbase0 + (size_t)(k_key + i * 32) * HID + k_col);
    vreg[i] = *(const u32x4*)(vbase + (size_t)(v_d + i * 64) * SLEN + v_cc);
  }
  #pragma unroll
  for (int i = 0; i < 2; ++i) {
    *(u32x4*)(Kld[0] + (k_key + i * 32) * 136 + k_col) = kreg[i];
    *(u32x4*)(Vtld[0] + (v_d + i * 64) * 72 + v_cc) = vreg[i];
  }
  #pragma unroll
  for (int i = 0; i < 2; ++i) {
    kreg[i] = *(const u32x4*)(kbase0 + (size_t)(64 + k_key + i * 32) * HID + k_col);
    vreg[i] = *(const u32x4*)(vbase + (size_t)(v_d + i * 64) * SLEN + 64 + v_cc);
  }
  asm volatile("s_waitcnt lgkmcnt(0)" ::: "memory");
  __builtin_amdgcn_s_barrier();

  for (int c0 = 0; c0 < SLEN; c0 += 64) {
    const int p = (c0 >> 6) & 1;
    const unsigned short* Kr = Kld[p];
    const unsigned short* Vr = Vtld[p];

    // stage chunk c+1 (held in regs) into the other buffer; then issue
    // global loads for chunk c+2 (land during compute of c and c+1)
    if (c0 + 64 < SLEN) {
      unsigned short* Kw = Kld[p ^ 1];
      unsigned short* Vw = Vtld[p ^ 1];
      #pragma unroll
      for (int i = 0; i < 2; ++i) {
        *(u32x4*)(Kw + (k_key + i * 32) * 136 + k_col) = kreg[i];
        *(u32x4*)(Vw + (v_d + i * 64) * 72 + v_cc) = vreg[i];
      }
      if (c0 + 128 < SLEN) {
        #pragma unroll
        for (int i = 0; i < 2; ++i) {
          kreg[i] = *(const u32x4*)(kbase0 + (size_t)(c0 + 128 + k_key + i * 32) * HID + k_col);
          vreg[i] = *(const u32x4*)(vbase + (size_t)(v_d + i * 64) * SLEN + c0 + 128 + v_cc);
        }
      }
    }

    // mask bits: 64 keys for this lane's q-row (used after QK^T)
    u32x2 mw = *(const u32x2*)(mq + (c0 >> 5));

    // S^T = (Q K^T)^T via swapped operands: lane l16 = q, regs = keys
    f32x4 sc[4];
    #pragma unroll
    for (int ni = 0; ni < 4; ++ni) sc[ni] = f32x4{0.f, 0.f, 0.f, 0.f};
    __builtin_amdgcn_s_setprio(1);
    #pragma unroll
    for (int kk = 0; kk < 4; ++kk) {
      #pragma unroll
      for (int ni = 0; ni < 4; ++ni) {
        short8 bb = *(const short8*)(Kr + (ni * 16 + l16) * 136 + kk * 32 + quad * 8);
        sc[ni] = __builtin_amdgcn_mfma_f32_16x16x32_bf16(bb, qa[kk], sc[ni], 0, 0, 0);
      }
    }
    __builtin_amdgcn_s_setprio(0);

    // p = mask ? exp2(s) : 0, packed to bf16 pairs in-register
    unsigned int pk[4][2];
    #pragma unroll
    for (int ni = 0; ni < 4; ++ni) {
      unsigned wsel = (ni < 2) ? mw[0] : mw[1];
      float pp[4];
      #pragma unroll
      for (int r = 0; r < 4; ++r) {
        int bit = (ni & 1) * 16 + quad * 4 + r;
        float e = __builtin_amdgcn_exp2f(sc[ni][r]);   // raw v_exp_f32
        pp[r] = ((wsel >> bit) & 1u) ? e : 0.f;
      }
      asm("v_cvt_pk_bf16_f32 %0, %1, %2" : "=v"(pk[ni][0]) : "v"(pp[0]), "v"(pp[1]));
      asm("v_cvt_pk_bf16_f32 %0, %1, %2" : "=v"(pk[ni][1]) : "v"(pp[2]), "v"(pp[3]));
    }

    // O += P @ V ; rowsum += P @ 1 ; P A-frags assembled via permlane swaps
    #pragma unroll
    for (int kb = 0; kb < 2; ++kb) {
      unsigned int c0w = pk[kb * 2][0], c2w = pk[kb * 2 + 1][0];
      asm("v_permlane32_swap_b32 %0, %1" : "+v"(c0w), "+v"(c2w));
      asm("v_permlane16_swap_b32 %0, %1" : "+v"(c0w), "+v"(c2w));
      unsigned int c1w = pk[kb * 2][1], c3w = pk[kb * 2 + 1][1];
      asm("v_permlane32_swap_b32 %0, %1" : "+v"(c1w), "+v"(c3w));
      asm("v_permlane16_swap_b32 %0, %1" : "+v"(c1w), "+v"(c3w));
      short8 a = __builtin_bit_cast(short8, u32x4{c0w, c1w, c2w, c3w});
      __builtin_amdgcn_s_setprio(1);
      #pragma unroll
      for (int nd = 0; nd < 8; ++nd) {
        short8 bv = *(const short8*)(Vr + (nd * 16 + l16) * 72 + kb * 32 + quad * 8);
        oc[nd] = __builtin_amdgcn_mfma_f32_16x16x32_bf16(a, bv, oc[nd], 0, 0, 0);
      }
      oc9 = __builtin_amdgcn_mfma_f32_16x16x32_bf16(a, ones, oc9, 0, 0, 0);
      __builtin_amdgcn_s_setprio(0);
    }

    // one barrier per chunk: own LDS writes visible, then all waves align.
    // vmcnt NOT drained -> c+2 loads stay in flight across the barrier.
    if (c0 + 64 < SLEN) {
      asm volatile("s_waitcnt lgkmcnt(0)" ::: "memory");
      __builtin_amdgcn_s_barrier();
    }
  }

  // D[q][d] epilogue: rcp once per row, multiply
  float rcp[4];
  #pragma unroll
  for (int r = 0; r < 4; ++r) rcp[r] = __builtin_amdgcn_rcpf(oc9[r]);
  #pragma unroll
  for (int nd = 0; nd < 8; ++nd)
    #pragma unroll
    for (int r = 0; r < 4; ++r) {
      float val = oc[nd][r] * rcp[r];
      int row = q0 + w * 16 + quad * 4 + r;
      int col = h * HID + nd * 16 + l16;
      ctx[(rowbase + row) * DPROJ + col] = f2bf(val);
    }
}

// ---------------------------------------------------------------------------
// Kernel 3: fused output projection + residual + LayerNorm (R8 version).
// ---------------------------------------------------------------------------
__global__ __launch_bounds__(256, 4) void oproj_ln_kernel(
    const unsigned short* __restrict__ ctx,   // (M,512) bf16
    const unsigned short* __restrict__ WoT,   // (128,512) bf16 n-major
    const float* __restrict__ enc,            // (M,128) fp32
    const float* __restrict__ gamma,
    const float* __restrict__ beta,
    float* __restrict__ out)                  // (M,128) fp32
{
  const int m0 = blockIdx.x * 64;
  const int t = threadIdx.x;
  const int lane = t & 63;
  const int w = t >> 6;
  const int quad = lane >> 4;
  const int l16 = lane & 15;

  __shared__ __align__(16) unsigned short Actx[64 * 72];
  __shared__ __align__(16) unsigned short Bw[128 * 72];

  f32x4 acc[8];
  #pragma unroll
  for (int ni = 0; ni < 8; ++ni) acc[ni] = f32x4{0.f, 0.f, 0.f, 0.f};

  for (int kc = 0; kc < DPROJ; kc += 64) {
    __syncthreads();
    #pragma unroll
    for (int i = 0; i < 2; ++i) {
      int idx = i * 256 + t;
      int row = idx >> 3;
      int col = (idx & 7) << 3;
      *(u32x4*)(Actx + row * 72 + col) =
          *(const u32x4*)(ctx + (size_t)(m0 + row) * DPROJ + kc + col);
    }
    #pragma unroll
    for (int i = 0; i < 4; ++i) {
      int idx = i * 256 + t;
      int row = idx >> 3;
      int col = (idx & 7) << 3;
      *(u32x4*)(Bw + row * 72 + col) =
          *(const u32x4*)(WoT + (size_t)row * DPROJ + kc + col);
    }
    __syncthreads();
    #pragma unroll
    for (int kk = 0; kk < 2; ++kk) {
      short8 a = *(const short8*)(Actx + (w * 16 + l16) * 72 + kk * 32 + quad * 8);
      #pragma unroll
      for (int ni = 0; ni < 8; ++ni) {
        short8 bb = *(const short8*)(Bw + (ni * 16 + l16) * 72 + kk * 32 + quad * 8);
        acc[ni] = __builtin_amdgcn_mfma_f32_16x16x32_bf16(a, bb, acc[ni], 0, 0, 0);
      }
    }
  }

  float g[8], be[8];
  #pragma unroll
  for (int ni = 0; ni < 8; ++ni) {
    g[ni] = gamma[ni * 16 + l16];
    be[ni] = beta[ni * 16 + l16];
  }

  float val[8][4];
  #pragma unroll
  for (int r = 0; r < 4; ++r) {
    int m = m0 + w * 16 + quad * 4 + r;
    const float* erow = enc + (size_t)m * HID;
    float s = 0.f, s2 = 0.f;
    #pragma unroll
    for (int ni = 0; ni < 8; ++ni) {
      float v = acc[ni][r] + erow[ni * 16 + l16];
      val[ni][r] = v;
      s += v;
      s2 += v * v;
    }
    #pragma unroll
    for (int off = 1; off < 16; off <<= 1) {
      s  += __shfl_xor(s, off, 64);
      s2 += __shfl_xor(s2, off, 64);
    }
    float mean = s * (1.f / 128.f);
    float var = s2 * (1.f / 128.f) - mean * mean;
    float rstd = rsqrtf(var + 1e-6f);
    float* orow = out + (size_t)m * HID;
    #pragma unroll
    for (int ni = 0; ni < 8; ++ni)
      orow[ni * 16 + l16] = g[ni] * (val[ni][r] - mean) * rstd + be[ni];
  }
}

// ---------------------------------------------------------------------------
// ws layout (elements):
//   WT   : 3*512*128 shorts        WoT : 128*512 shorts
//   Qh   : 4*M*128 shorts          Kh  : 4*M*128 shorts
//   Vt   : 4*64*128*512 shorts     ctx : M*512 shorts
//   encb : M*128 shorts (fp32-sized slot)
//   mbits: 64*512*16 u32           (~153.6 MB total)
// ---------------------------------------------------------------------------
extern "C" void kernel_launch(void* const* d_in, const int* in_sizes, int n_in,
                              void* d_out, int out_size, void* d_ws, size_t ws_size,
                              hipStream_t stream) {
  const float* enc   = (const float*)d_in[0];
  const int*   mask  = (const int*)d_in[1];
  const float* Wq    = (const float*)d_in[2];
  const float* Wk    = (const float*)d_in[3];
  const float* Wv    = (const float*)d_in[4];
  const float* Wo    = (const float*)d_in[5];
  const float* gamma = (const float*)d_in[6];
  const float* beta  = (const float*)d_in[7];
  float* out = (float*)d_out;

  unsigned short* WT  = (unsigned short*)d_ws;
  unsigned short* WoT = WT + (size_t)3 * DPROJ * HID;
  unsigned short* Qh  = WoT + (size_t)HID * DPROJ;
  unsigned short* Kh  = Qh + (size_t)NHEAD * MTOT * HID;
  unsigned short* Vt  = Kh + (size_t)NHEAD * MTOT * HID;
  unsigned short* ctx = Vt + (size_t)NHEAD * MTOT * HID;
  unsigned short* encb = ctx + (size_t)MTOT * DPROJ;
  unsigned int* mbits = (unsigned int*)(encb + (size_t)MTOT * HID * 2);

  prep_kernel<<<19456, 256, 0, stream>>>(Wq, Wk, Wv, Wo, enc, mask, WT, WoT, encb, mbits);
  qkv_kernel<<<dim3(4, 256), 256, 0, stream>>>(encb, WT, Qh, Kh, Vt);
  attn_kernel<<<1024, 512, 0, stream>>>(Qh, Kh, Vt, mbits, ctx);
  oproj_ln_kernel<<<MTOT / 64, 256, 0, stream>>>(ctx, WoT, enc, gamma, beta, out);
}

// Round 4
// 222.907 us; speedup vs baseline: 1.3998x; 1.0245x over previous
//
#include <hip/hip_runtime.h>
#include <stdint.h>

#define BATCH 64
#define SLEN 512
#define HID 128
#define NHEAD 4
#define DPROJ 512            // HID * NHEAD
#define MTOT (BATCH * SLEN)  // 32768
#define SCALE 0.08838834764831845f
#define LOG2E 1.4426950408889634f

using short8 = __attribute__((ext_vector_type(8))) short;
using f32x4  = __attribute__((ext_vector_type(4))) float;
using u32x4  = __attribute__((ext_vector_type(4))) unsigned int;
using u32x2  = __attribute__((ext_vector_type(2))) unsigned int;
using us4    = __attribute__((ext_vector_type(4))) unsigned short;

__device__ __forceinline__ unsigned short f2bf(float f) {
  unsigned int u = __float_as_uint(f);
  u += 0x7fffu + ((u >> 16) & 1u);   // round-to-nearest-even
  return (unsigned short)(u >> 16);
}

// ---------------------------------------------------------------------------
// Kernel 0: prep. blocks 0..1023: weight cast+transpose (Wq pre-scaled by
// SCALE*log2(e) so attn uses exp2). blocks 1024..3071: enc fp32->bf16.
// blocks 3072..19455: mask -> bitmask. (frozen; ~BW floor)
// ---------------------------------------------------------------------------
__global__ __launch_bounds__(256) void prep_kernel(
    const float* __restrict__ Wq,
    const float* __restrict__ Wk,
    const float* __restrict__ Wv,
    const float* __restrict__ Wo,
    const float* __restrict__ enc,
    const int* __restrict__ mask,
    unsigned short* __restrict__ WT,
    unsigned short* __restrict__ WoT,
    unsigned short* __restrict__ encb,
    unsigned int* __restrict__ mbits)
{
  if (blockIdx.x < 1024) {
    int idx = blockIdx.x * 256 + threadIdx.x;
    int z = idx >> 16;
    int i = idx & 65535;
    if (z < 3) {
      const float* W = (z == 0) ? Wq : (z == 1) ? Wk : Wv;
      float scale = (z == 0) ? (SCALE * LOG2E) : 1.0f;  // exp2 form
      int k = i >> 9;
      int n = i & 511;
      WT[(size_t)z * 65536 + (size_t)n * 128 + k] = f2bf(W[i] * scale);
    } else {
      int k = i >> 7;
      int n = i & 127;
      WoT[(size_t)n * 512 + k] = f2bf(Wo[i]);
    }
  } else if (blockIdx.x < 3072) {
    size_t tid = (size_t)(blockIdx.x - 1024) * 256 + threadIdx.x;  // 0..524287
    const float* s = enc + tid * 8;
    f32x4 a0 = *(const f32x4*)(s);
    f32x4 a1 = *(const f32x4*)(s + 4);
    short8 v;
    #pragma unroll
    for (int j = 0; j < 4; ++j) v[j] = (short)f2bf(a0[j]);
    #pragma unroll
    for (int j = 0; j < 4; ++j) v[4 + j] = (short)f2bf(a1[j]);
    *(short8*)(encb + tid * 8) = v;
  } else {
    const int l = threadIdx.x & 63;
    size_t wavebase = (size_t)(blockIdx.x - 3072) * 1024 + (threadIdx.x >> 6) * 256;
    unsigned long long b0 = __ballot(mask[wavebase + 0 * 64 + l] != 0);
    unsigned long long b1 = __ballot(mask[wavebase + 1 * 64 + l] != 0);
    unsigned long long b2 = __ballot(mask[wavebase + 2 * 64 + l] != 0);
    unsigned long long b3 = __ballot(mask[wavebase + 3 * 64 + l] != 0);
    if (l < 4) {
      unsigned long long v = (l & 2) ? ((l & 1) ? b3 : b2) : ((l & 1) ? b1 : b0);
      *(unsigned long long*)(mbits + (wavebase >> 5) + l * 2) = v;
    }
  }
}

// ---------------------------------------------------------------------------
// Kernel 1: QKV projection — R14. R13's proven pipeline pattern applied:
// 6 stages s=(z,kc); B(s+1) prefetched in regs, written to Bld[p^1] after
// compute(s); B(s+2) global loads issued immediately after (land during
// next compute). ONE lgkm-only barrier per stage (was 2 full syncthreads);
// vmcnt never drained at barriers. LDS 53,248 -> 71,680 B (2 blocks/CU;
// latency hiding now from prefetch, not TLP). A staged once, unchanged.
// ---------------------------------------------------------------------------
__global__ __launch_bounds__(256) void qkv_kernel(
    const unsigned short* __restrict__ encb,  // (M,128) bf16
    const unsigned short* __restrict__ WT,    // (3,512,128) bf16 n-major
    unsigned short* __restrict__ Qh,
    unsigned short* __restrict__ Kh,
    unsigned short* __restrict__ Vt)
{
  const int nt = blockIdx.x;   // 0..3 == head
  const int mt = blockIdx.y;   // 0..255
  const int t = threadIdx.x;
  const int lane = t & 63;
  const int w = t >> 6;
  const int quad = lane >> 4;
  const int l16 = lane & 15;

  __shared__ __align__(16) unsigned short Ald[128 * 136];     // 34816 B
  __shared__ __align__(16) unsigned short Bld[2][128 * 72];   // 36864 B

  const int m0 = mt * 128, n0 = nt * 128;
  const int wm = (w >> 1) * 64, wn = (w & 1) * 64;

  const int b_row = t >> 3, b_col = (t & 7) << 3;  // B-stage: +32 rows per i

  // prologue: A -> regs -> Ald; B(s=0) -> regs -> Bld[0]; B(s=1) -> regs
  {
    u32x4 areg[8];
    #pragma unroll
    for (int i = 0; i < 8; ++i) {
      int idx = i * 256 + t;
      areg[i] = *(const u32x4*)(encb + (size_t)(m0 + (idx >> 4)) * HID + ((idx & 15) << 3));
    }
    u32x4 breg0[4];
    #pragma unroll
    for (int i = 0; i < 4; ++i)
      breg0[i] = *(const u32x4*)(WT + (size_t)(n0 + b_row + i * 32) * HID + b_col);
    #pragma unroll
    for (int i = 0; i < 8; ++i) {
      int idx = i * 256 + t;
      *(u32x4*)(Ald + (idx >> 4) * 136 + ((idx & 15) << 3)) = areg[i];
    }
    #pragma unroll
    for (int i = 0; i < 4; ++i)
      *(u32x4*)(Bld[0] + (b_row + i * 32) * 72 + b_col) = breg0[i];
  }
  u32x4 breg[4];
  #pragma unroll
  for (int i = 0; i < 4; ++i)   // s=1: z=0, kc=1
    breg[i] = *(const u32x4*)(WT + (size_t)(n0 + b_row + i * 32) * HID + 64 + b_col);
  asm volatile("s_waitcnt lgkmcnt(0)" ::: "memory");
  __builtin_amdgcn_s_barrier();

  f32x4 acc[4][4];
  #pragma unroll
  for (int s = 0; s < 6; ++s) {
    const int z = s >> 1, kc = s & 1, p = s & 1;
    if (kc == 0) {
      #pragma unroll
      for (int mi = 0; mi < 4; ++mi)
        #pragma unroll
        for (int ni = 0; ni < 4; ++ni)
          acc[mi][ni] = f32x4{0.f, 0.f, 0.f, 0.f};
    }

    const unsigned short* Br = Bld[p];
    #pragma unroll
    for (int kk = 0; kk < 2; ++kk) {
      short8 a[4], bb[4];
      #pragma unroll
      for (int mi = 0; mi < 4; ++mi)
        a[mi] = *(const short8*)(Ald + (wm + mi * 16 + l16) * 136 + kc * 64 + kk * 32 + quad * 8);
      #pragma unroll
      for (int ni = 0; ni < 4; ++ni)
        bb[ni] = *(const short8*)(Br + (wn + ni * 16 + l16) * 72 + kk * 32 + quad * 8);
      if (z < 2) {
        #pragma unroll
        for (int mi = 0; mi < 4; ++mi)
          #pragma unroll
          for (int ni = 0; ni < 4; ++ni)
            acc[mi][ni] = __builtin_amdgcn_mfma_f32_16x16x32_bf16(bb[ni], a[mi], acc[mi][ni], 0, 0, 0);
      } else {
        #pragma unroll
        for (int mi = 0; mi < 4; ++mi)
          #pragma unroll
          for (int ni = 0; ni < 4; ++ni)
            acc[mi][ni] = __builtin_amdgcn_mfma_f32_16x16x32_bf16(a[mi], bb[ni], acc[mi][ni], 0, 0, 0);
      }
    }

    if (s < 5) {
      // write prefetched B(s+1) into the idle buffer; issue loads for s+2
      unsigned short* Bw2 = Bld[p ^ 1];
      #pragma unroll
      for (int i = 0; i < 4; ++i)
        *(u32x4*)(Bw2 + (b_row + i * 32) * 72 + b_col) = breg[i];
      if (s < 4) {
        const int s2 = s + 2;
        const unsigned short* Wz = WT + (size_t)(s2 >> 1) * DPROJ * HID;
        #pragma unroll
        for (int i = 0; i < 4; ++i)
          breg[i] = *(const u32x4*)(Wz + (size_t)(n0 + b_row + i * 32) * HID + (s2 & 1) * 64 + b_col);
      }
      asm volatile("s_waitcnt lgkmcnt(0)" ::: "memory");
      __builtin_amdgcn_s_barrier();
    }

    if (kc == 1) {
      if (z < 2) {
        // D[n][m]: col(l16)=m-within-16, row(quad*4+r)=d-within-16
        unsigned short* outz = ((z == 0) ? Qh : Kh) + (size_t)nt * MTOT * HID;
        #pragma unroll
        for (int mi = 0; mi < 4; ++mi)
          #pragma unroll
          for (int ni = 0; ni < 4; ++ni) {
            int m = m0 + wm + mi * 16 + l16;
            int dbase = wn + ni * 16 + quad * 4;
            us4 pk;
            #pragma unroll
            for (int r = 0; r < 4; ++r) pk[r] = f2bf(acc[mi][ni][r]);
            *(us4*)(outz + (size_t)m * HID + dbase) = pk;
          }
      } else {
        // D[m][n]: reg axis = s (4 consecutive) -> Vt[(nt*B+b)*128 + d][s]
        #pragma unroll
        for (int mi = 0; mi < 4; ++mi)
          #pragma unroll
          for (int ni = 0; ni < 4; ++ni) {
            int row0 = m0 + wm + mi * 16 + quad * 4;
            int b = row0 >> 9, sres = row0 & 511;
            int d = wn + ni * 16 + l16;
            us4 pk;
            #pragma unroll
            for (int r = 0; r < 4; ++r) pk[r] = f2bf(acc[mi][ni][r]);
            *(us4*)(Vt + ((size_t)(nt * BATCH + b) * HID + d) * SLEN + sres) = pk;
          }
      }
    }
  }
}

// ---------------------------------------------------------------------------
// Kernel 2: flash attention — R13 (frozen; measured 55.1us, VGPR 60).
// ---------------------------------------------------------------------------
__global__ __launch_bounds__(512, 4) void attn_kernel(
    const unsigned short* __restrict__ Qh,   // (NH, M, 128)
    const unsigned short* __restrict__ Kh,   // (NH, M, 128)
    const unsigned short* __restrict__ Vt,   // (NH, B, 128, S)
    const unsigned int* __restrict__ mbits,  // (B, S, 16)
    unsigned short* __restrict__ ctx)        // (M, 512)
{
  const int lin = blockIdx.x;              // 0..1023
  const int work = (lin & 7) * 128 + (lin >> 3);
  const int qt = work & 3;
  const int h  = (work >> 2) & 3;
  const int b  = work >> 4;

  const int t = threadIdx.x;
  const int lane = t & 63;
  const int w = t >> 6;                    // 0..7
  const int quad = lane >> 4;
  const int l16 = lane & 15;

  __shared__ __align__(16) unsigned short Kld[2][64 * 136];   // 34816 B
  __shared__ __align__(16) unsigned short Vtld[2][128 * 72];  // 36864 B

  const int q0 = qt * 128;
  const size_t rowbase = (size_t)b * SLEN;
  const unsigned short* kbase0 = Kh + ((size_t)h * MTOT + rowbase) * HID;
  const unsigned short* vbase  = Vt + (size_t)(h * BATCH + b) * HID * SLEN;
  const unsigned int* mrow = mbits + (size_t)b * SLEN * 16;

  const int k_key = t >> 4, k_col = (t & 15) << 3;   // +32 keys at i=1
  const int v_d   = t >> 3, v_cc  = (t & 7) << 3;    // +64 d at i=1

  short8 qa[4];
  {
    const unsigned short* qbase =
        Qh + ((size_t)h * MTOT + rowbase + q0 + w * 16 + l16) * HID + quad * 8;
    #pragma unroll
    for (int kk = 0; kk < 4; ++kk)
      qa[kk] = *(const short8*)(qbase + kk * 32);
  }

  short8 ones;
  #pragma unroll
  for (int j = 0; j < 8; ++j) ones[j] = (short)0x3F80;  // bf16 1.0

  f32x4 oc[8], oc9;
  #pragma unroll
  for (int nd = 0; nd < 8; ++nd) oc[nd] = f32x4{0.f, 0.f, 0.f, 0.f};
  oc9 = f32x4{0.f, 0.f, 0.f, 0.f};

  // per-lane q-row is fixed: one mask base
  const unsigned int* mq = mrow + (size_t)(q0 + w * 16 + l16) * 16;

  // prologue: load chunk 0 -> regs -> buf0; load chunk 1 -> regs; barrier
  u32x4 kreg[2], vreg[2];
  #pragma unroll
  for (int i = 0; i < 2; ++i) {
    kreg[i] = *(const u32x4*)(kbase0 + (size_t)(k_key + i * 32) * HID + k_col);
    vreg[i] = *(const u32x4*)(vbase + (size_t)(v_d + i * 64) * SLEN + v_cc);
  }
  #pragma unroll
  for (int i = 0; i < 2; ++i) {
    *(u32x4*)(Kld[0] + (k_key + i * 32) * 136 + k_col) = kreg[i];
    *(u32x4*)(Vtld[0] + (v_d + i * 64) * 72 + v_cc) = vreg[i];
  }
  #pragma unroll
  for (int i = 0; i < 2; ++i) {
    kreg[i] = *(const u32x4*)(kbase0 + (size_t)(64 + k_key + i * 32) * HID + k_col);
    vreg[i] = *(const u32x4*)(vbase + (size_t)(v_d + i * 64) * SLEN + 64 + v_cc);
  }
  asm volatile("s_waitcnt lgkmcnt(0)" ::: "memory");
  __builtin_amdgcn_s_barrier();

  for (int c0 = 0; c0 < SLEN; c0 += 64) {
    const int p = (c0 >> 6) & 1;
    const unsigned short* Kr = Kld[p];
    const unsigned short* Vr = Vtld[p];

    // stage chunk c+1 (held in regs) into the other buffer; then issue
    // global loads for chunk c+2 (land during compute of c and c+1)
    if (c0 + 64 < SLEN) {
      unsigned short* Kw = Kld[p ^ 1];
      unsigned short* Vw = Vtld[p ^ 1];
      #pragma unroll
      for (int i = 0; i < 2; ++i) {
        *(u32x4*)(Kw + (k_key + i * 32) * 136 + k_col) = kreg[i];
        *(u32x4*)(Vw + (v_d + i * 64) * 72 + v_cc) = vreg[i];
      }
      if (c0 + 128 < SLEN) {
        #pragma unroll
        for (int i = 0; i < 2; ++i) {
          kreg[i] = *(const u32x4*)(kbase0 + (size_t)(c0 + 128 + k_key + i * 32) * HID + k_col);
          vreg[i] = *(const u32x4*)(vbase + (size_t)(v_d + i * 64) * SLEN + c0 + 128 + v_cc);
        }
      }
    }

    // mask bits: 64 keys for this lane's q-row (used after QK^T)
    u32x2 mw = *(const u32x2*)(mq + (c0 >> 5));

    // S^T = (Q K^T)^T via swapped operands: lane l16 = q, regs = keys
    f32x4 sc[4];
    #pragma unroll
    for (int ni = 0; ni < 4; ++ni) sc[ni] = f32x4{0.f, 0.f, 0.f, 0.f};
    __builtin_amdgcn_s_setprio(1);
    #pragma unroll
    for (int kk = 0; kk < 4; ++kk) {
      #pragma unroll
      for (int ni = 0; ni < 4; ++ni) {
        short8 bb = *(const short8*)(Kr + (ni * 16 + l16) * 136 + kk * 32 + quad * 8);
        sc[ni] = __builtin_amdgcn_mfma_f32_16x16x32_bf16(bb, qa[kk], sc[ni], 0, 0, 0);
      }
    }
    __builtin_amdgcn_s_setprio(0);

    // p = mask ? exp2(s) : 0, packed to bf16 pairs in-register
    unsigned int pk[4][2];
    #pragma unroll
    for (int ni = 0; ni < 4; ++ni) {
      unsigned wsel = (ni < 2) ? mw[0] : mw[1];
      float pp[4];
      #pragma unroll
      for (int r = 0; r < 4; ++r) {
        int bit = (ni & 1) * 16 + quad * 4 + r;
        float e = __builtin_amdgcn_exp2f(sc[ni][r]);   // raw v_exp_f32
        pp[r] = ((wsel >> bit) & 1u) ? e : 0.f;
      }
      asm("v_cvt_pk_bf16_f32 %0, %1, %2" : "=v"(pk[ni][0]) : "v"(pp[0]), "v"(pp[1]));
      asm("v_cvt_pk_bf16_f32 %0, %1, %2" : "=v"(pk[ni][1]) : "v"(pp[2]), "v"(pp[3]));
    }

    // O += P @ V ; rowsum += P @ 1 ; P A-frags assembled via permlane swaps
    #pragma unroll
    for (int kb = 0; kb < 2; ++kb) {
      unsigned int c0w = pk[kb * 2][0], c2w = pk[kb * 2 + 1][0];
      asm("v_permlane32_swap_b32 %0, %1" : "+v"(c0w), "+v"(c2w));
      asm("v_permlane16_swap_b32 %0, %1" : "+v"(c0w), "+v"(c2w));
      unsigned int c1w = pk[kb * 2][1], c3w = pk[kb * 2 + 1][1];
      asm("v_permlane32_swap_b32 %0, %1" : "+v"(c1w), "+v"(c3w));
      asm("v_permlane16_swap_b32 %0, %1" : "+v"(c1w), "+v"(c3w));
      short8 a = __builtin_bit_cast(short8, u32x4{c0w, c1w, c2w, c3w});
      __builtin_amdgcn_s_setprio(1);
      #pragma unroll
      for (int nd = 0; nd < 8; ++nd) {
        short8 bv = *(const short8*)(Vr + (nd * 16 + l16) * 72 + kb * 32 + quad * 8);
        oc[nd] = __builtin_amdgcn_mfma_f32_16x16x32_bf16(a, bv, oc[nd], 0, 0, 0);
      }
      oc9 = __builtin_amdgcn_mfma_f32_16x16x32_bf16(a, ones, oc9, 0, 0, 0);
      __builtin_amdgcn_s_setprio(0);
    }

    // one barrier per chunk: own LDS writes visible, then all waves align.
    // vmcnt NOT drained -> c+2 loads stay in flight across the barrier.
    if (c0 + 64 < SLEN) {
      asm volatile("s_waitcnt lgkmcnt(0)" ::: "memory");
      __builtin_amdgcn_s_barrier();
    }
  }

  // D[q][d] epilogue: rcp once per row, multiply
  float rcp[4];
  #pragma unroll
  for (int r = 0; r < 4; ++r) rcp[r] = __builtin_amdgcn_rcpf(oc9[r]);
  #pragma unroll
  for (int nd = 0; nd < 8; ++nd)
    #pragma unroll
    for (int r = 0; r < 4; ++r) {
      float val = oc[nd][r] * rcp[r];
      int row = q0 + w * 16 + quad * 4 + r;
      int col = h * HID + nd * 16 + l16;
      ctx[(rowbase + row) * DPROJ + col] = f2bf(val);
    }
}

// ---------------------------------------------------------------------------
// Kernel 3: output projection + residual + LayerNorm — R14. Same pipeline
// treatment: double-buffered Actx/Bw (LDS 27.6K -> 55.3K; grid is 512 =
// exactly 2 blocks/CU either way, so occupancy cost is zero), A/B(kc+1)
// prefetched in regs during compute(kc), single lgkm-only barrier per iter
// (was 2 full syncthreads draining vmcnt). launch_bounds (256,2) matches
// physical residency and removes VGPR cap (peak liveness ~100, no spill).
// ---------------------------------------------------------------------------
__global__ __launch_bounds__(256, 2) void oproj_ln_kernel(
    const unsigned short* __restrict__ ctx,   // (M,512) bf16
    const unsigned short* __restrict__ WoT,   // (128,512) bf16 n-major
    const float* __restrict__ enc,            // (M,128) fp32
    const float* __restrict__ gamma,
    const float* __restrict__ beta,
    float* __restrict__ out)                  // (M,128) fp32
{
  const int m0 = blockIdx.x * 64;
  const int t = threadIdx.x;
  const int lane = t & 63;
  const int w = t >> 6;
  const int quad = lane >> 4;
  const int l16 = lane & 15;

  __shared__ __align__(16) unsigned short Actx[2][64 * 72];   // 18432 B
  __shared__ __align__(16) unsigned short Bw[2][128 * 72];    // 36864 B

  const int a_row = t >> 3, a_col = (t & 7) << 3;   // +32 rows at i=1 (64 rows)
  const int b_row = t >> 3, b_col = (t & 7) << 3;   // +32 rows per i (128 rows)

  f32x4 acc[8];
  #pragma unroll
  for (int ni = 0; ni < 8; ++ni) acc[ni] = f32x4{0.f, 0.f, 0.f, 0.f};

  // prologue: (kc=0) -> regs -> buf0; (kc=1) -> regs; barrier
  u32x4 areg[2], breg[4];
  #pragma unroll
  for (int i = 0; i < 2; ++i)
    areg[i] = *(const u32x4*)(ctx + (size_t)(m0 + a_row + i * 32) * DPROJ + a_col);
  #pragma unroll
  for (int i = 0; i < 4; ++i)
    breg[i] = *(const u32x4*)(WoT + (size_t)(b_row + i * 32) * DPROJ + b_col);
  #pragma unroll
  for (int i = 0; i < 2; ++i)
    *(u32x4*)(Actx[0] + (a_row + i * 32) * 72 + a_col) = areg[i];
  #pragma unroll
  for (int i = 0; i < 4; ++i)
    *(u32x4*)(Bw[0] + (b_row + i * 32) * 72 + b_col) = breg[i];
  #pragma unroll
  for (int i = 0; i < 2; ++i)
    areg[i] = *(const u32x4*)(ctx + (size_t)(m0 + a_row + i * 32) * DPROJ + 64 + a_col);
  #pragma unroll
  for (int i = 0; i < 4; ++i)
    breg[i] = *(const u32x4*)(WoT + (size_t)(b_row + i * 32) * DPROJ + 64 + b_col);
  asm volatile("s_waitcnt lgkmcnt(0)" ::: "memory");
  __builtin_amdgcn_s_barrier();

  #pragma unroll
  for (int it = 0; it < 8; ++it) {
    const int p = it & 1;
    const unsigned short* Ar = Actx[p];
    const unsigned short* Br = Bw[p];
    #pragma unroll
    for (int kk = 0; kk < 2; ++kk) {
      short8 a = *(const short8*)(Ar + (w * 16 + l16) * 72 + kk * 32 + quad * 8);
      #pragma unroll
      for (int ni = 0; ni < 8; ++ni) {
        short8 bb = *(const short8*)(Br + (ni * 16 + l16) * 72 + kk * 32 + quad * 8);
        acc[ni] = __builtin_amdgcn_mfma_f32_16x16x32_bf16(a, bb, acc[ni], 0, 0, 0);
      }
    }
    if (it < 7) {
      unsigned short* Aw2 = Actx[p ^ 1];
      unsigned short* Bw2 = Bw[p ^ 1];
      #pragma unroll
      for (int i = 0; i < 2; ++i)
        *(u32x4*)(Aw2 + (a_row + i * 32) * 72 + a_col) = areg[i];
      #pragma unroll
      for (int i = 0; i < 4; ++i)
        *(u32x4*)(Bw2 + (b_row + i * 32) * 72 + b_col) = breg[i];
      if (it < 6) {
        const int kc2 = (it + 2) * 64;
        #pragma unroll
        for (int i = 0; i < 2; ++i)
          areg[i] = *(const u32x4*)(ctx + (size_t)(m0 + a_row + i * 32) * DPROJ + kc2 + a_col);
        #pragma unroll
        for (int i = 0; i < 4; ++i)
          breg[i] = *(const u32x4*)(WoT + (size_t)(b_row + i * 32) * DPROJ + kc2 + b_col);
      }
      asm volatile("s_waitcnt lgkmcnt(0)" ::: "memory");
      __builtin_amdgcn_s_barrier();
    }
  }

  float g[8], be[8];
  #pragma unroll
  for (int ni = 0; ni < 8; ++ni) {
    g[ni] = gamma[ni * 16 + l16];
    be[ni] = beta[ni * 16 + l16];
  }

  float val[8][4];
  #pragma unroll
  for (int r = 0; r < 4; ++r) {
    int m = m0 + w * 16 + quad * 4 + r;
    const float* erow = enc + (size_t)m * HID;
    float s = 0.f, s2 = 0.f;
    #pragma unroll
    for (int ni = 0; ni < 8; ++ni) {
      float v = acc[ni][r] + erow[ni * 16 + l16];
      val[ni][r] = v;
      s += v;
      s2 += v * v;
    }
    #pragma unroll
    for (int off = 1; off < 16; off <<= 1) {
      s  += __shfl_xor(s, off, 64);
      s2 += __shfl_xor(s2, off, 64);
    }
    float mean = s * (1.f / 128.f);
    float var = s2 * (1.f / 128.f) - mean * mean;
    float rstd = rsqrtf(var + 1e-6f);
    float* orow = out + (size_t)m * HID;
    #pragma unroll
    for (int ni = 0; ni < 8; ++ni)
      orow[ni * 16 + l16] = g[ni] * (val[ni][r] - mean) * rstd + be[ni];
  }
}

// ---------------------------------------------------------------------------
// ws layout (elements):
//   WT   : 3*512*128 shorts        WoT : 128*512 shorts
//   Qh   : 4*M*128 shorts          Kh  : 4*M*128 shorts
//   Vt   : 4*64*128*512 shorts     ctx : M*512 shorts
//   encb : M*128 shorts (fp32-sized slot)
//   mbits: 64*512*16 u32           (~153.6 MB total)
// ---------------------------------------------------------------------------
extern "C" void kernel_launch(void* const* d_in, const int* in_sizes, int n_in,
                              void* d_out, int out_size, void* d_ws, size_t ws_size,
                              hipStream_t stream) {
  const float* enc   = (const float*)d_in[0];
  const int*   mask  = (const int*)d_in[1];
  const float* Wq    = (const float*)d_in[2];
  const float* Wk    = (const float*)d_in[3];
  const float* Wv    = (const float*)d_in[4];
  const float* Wo    = (const float*)d_in[5];
  const float* gamma = (const float*)d_in[6];
  const float* beta  = (const float*)d_in[7];
  float* out = (float*)d_out;

  unsigned short* WT  = (unsigned short*)d_ws;
  unsigned short* WoT = WT + (size_t)3 * DPROJ * HID;
  unsigned short* Qh  = WoT + (size_t)HID * DPROJ;
  unsigned short* Kh  = Qh + (size_t)NHEAD * MTOT * HID;
  unsigned short* Vt  = Kh + (size_t)NHEAD * MTOT * HID;
  unsigned short* ctx = Vt + (size_t)NHEAD * MTOT * HID;
  unsigned short* encb = ctx + (size_t)MTOT * DPROJ;
  unsigned int* mbits = (unsigned int*)(encb + (size_t)MTOT * HID * 2);

  prep_kernel<<<19456, 256, 0, stream>>>(Wq, Wk, Wv, Wo, enc, mask, WT, WoT, encb, mbits);
  qkv_kernel<<<dim3(4, 256), 256, 0, stream>>>(encb, WT, Qh, Kh, Vt);
  attn_kernel<<<1024, 512, 0, stream>>>(Qh, Kh, Vt, mbits, ctx);
  oproj_ln_kernel<<<MTOT / 64, 256, 0, stream>>>(ctx, WoT, enc, gamma, beta, out);
}